// Round 5
// baseline (901.219 us; speedup 1.0000x reference)
//
#include <hip/hip_runtime.h>
#include <hip/hip_bf16.h>

#define LTOT 4096
#define DM 256
#define BATCH 8
#define MROWS (BATCH * LTOT)     // 32768
#define NX ((size_t)MROWS * DM)  // 8388608 elements

typedef __bf16 bf16x8 __attribute__((ext_vector_type(8)));
typedef float f32x4 __attribute__((ext_vector_type(4)));

__device__ __forceinline__ float elu1(float x) {
    return x > 0.f ? x + 1.f : expf(x);
}
__device__ __forceinline__ ushort f2bf(float f) {
    unsigned u = __float_as_uint(f);
    u += 0x7FFFu + ((u >> 16) & 1u);
    return (ushort)(u >> 16);
}
__device__ __forceinline__ unsigned pkbf(float a, float b) {
    return (unsigned)f2bf(a) | ((unsigned)f2bf(b) << 16);
}
__device__ __forceinline__ float b2f(ushort u) {
    return __uint_as_float(((unsigned)u) << 16);
}

// ---------------------------------------------------------------------------
// prep: X[b,l,c] = feats[b,c,l] + pos(c,l) (fp32); XC left half = bf16(same)
// ---------------------------------------------------------------------------
__global__ __launch_bounds__(256) void prep_kernel(const float* __restrict__ feats,
                                                   float* __restrict__ X,
                                                   ushort* __restrict__ XC) {
    __shared__ float tile[32][33];
    int b = blockIdx.z;
    int l0 = blockIdx.x * 32;
    int c0 = blockIdx.y * 32;
    int tx = threadIdx.x, ty = threadIdx.y;
#pragma unroll
    for (int j = 0; j < 4; ++j) {
        int c = c0 + ty + j * 8;
        tile[ty + j * 8][tx] = feats[((size_t)(b * DM + c)) * LTOT + l0 + tx];
    }
    __syncthreads();
#pragma unroll
    for (int j = 0; j < 4; ++j) {
        int l = l0 + ty + j * 8;
        int c = c0 + tx;
        int i2 = (c >> 2) * 2;
        float dv = expf((float)i2 * -0.07195578415156063f);
        int rem = c & 3;
        int y = l >> 6, xc = l & 63;
        float pos = (rem < 2) ? (float)(xc + 1) : (float)(y + 1);
        float arg = pos * dv;
        float pe = (rem & 1) ? cosf(arg) : sinf(arg);
        float val = tile[tx][ty + j * 8] + pe;
        size_t row = (size_t)(b * LTOT + l);
        X[row * DM + c] = val;
        XC[row * 512 + c] = f2bf(val);
    }
}

__global__ __launch_bounds__(256) void unprep_kernel(const float* __restrict__ X,
                                                     float* __restrict__ out) {
    __shared__ float tile[32][33];
    int b = blockIdx.z;
    int l0 = blockIdx.x * 32;
    int c0 = blockIdx.y * 32;
    int tx = threadIdx.x, ty = threadIdx.y;
#pragma unroll
    for (int j = 0; j < 4; ++j) {
        int l = l0 + ty + j * 8;
        tile[ty + j * 8][tx] = X[((size_t)(b * LTOT + l)) * DM + c0 + tx];
    }
    __syncthreads();
#pragma unroll
    for (int j = 0; j < 4; ++j) {
        int c = c0 + ty + j * 8;
        out[((size_t)(b * DM + c)) * LTOT + l0 + tx] = tile[tx][ty + j * 8];
    }
}

// ---------------------------------------------------------------------------
// ALL weight transposes in one dispatch. blockIdx.x routes:
// [0,256)Wq [256,512)Wk [512,768)Wv [768,1024)Wm [1024,2048)W1 [2048,2560)W2
// ---------------------------------------------------------------------------
__global__ __launch_bounds__(256) void wtrans_all(const float* __restrict__ Wq,
                                                  const float* __restrict__ Wk,
                                                  const float* __restrict__ Wv,
                                                  const float* __restrict__ Wm,
                                                  const float* __restrict__ W1,
                                                  const float* __restrict__ W2,
                                                  ushort* __restrict__ WTqkv,
                                                  ushort* __restrict__ WTm,
                                                  ushort* __restrict__ WT1,
                                                  ushort* __restrict__ WT2) {
    __shared__ float t[32][33];
    int idx = blockIdx.x;
    const float* W;
    ushort* WT;
    int K, N, KT, z, r;
    size_t in_ls, out_ls;
    if (idx < 1024) {
        int which = idx >> 8, local = idx & 255;
        K = 256; N = 256; KT = 8; in_ls = 65536;
        if (which == 0)      { W = Wq; WT = WTqkv;          out_ls = 196608; }
        else if (which == 1) { W = Wk; WT = WTqkv + 65536;  out_ls = 196608; }
        else if (which == 2) { W = Wv; WT = WTqkv + 131072; out_ls = 196608; }
        else                 { W = Wm; WT = WTm;            out_ls = 65536; }
        z = local >> 6; r = local & 63;
    } else if (idx < 2048) {
        int local = idx - 1024;
        K = 512; N = 512; KT = 16; in_ls = 262144; out_ls = 262144;
        W = W1; WT = WT1;
        z = local >> 8; r = local & 255;
    } else {
        int local = idx - 2048;
        K = 512; N = 256; KT = 16; in_ls = 131072; out_ls = 131072;
        W = W2; WT = WT2;
        z = local >> 7; r = local & 127;
    }
    int k0 = (r % KT) * 32, n0 = (r / KT) * 32;
    const float* Wz = W + (size_t)z * in_ls;
    ushort* WTz = WT + (size_t)z * out_ls;
    int tx = threadIdx.x & 31, ty = threadIdx.x >> 5;
#pragma unroll
    for (int j = 0; j < 4; ++j)
        t[ty + j * 8][tx] = Wz[(size_t)(k0 + ty + j * 8) * N + n0 + tx];
    __syncthreads();
#pragma unroll
    for (int j = 0; j < 4; ++j)
        WTz[(size_t)(n0 + ty + j * 8) * K + k0 + tx] = f2bf(t[tx][ty + j * 8]);
}

// ---------------------------------------------------------------------------
// bf16 MFMA GEMM (round-3 proven config): Cb[M,N] = act(A[M,K] @ Bt[N,K]^T)
// 128x128 tile, BK=32, 4 waves 2x2, 4x4 frags of 16x16x32.
// ACT: 2 relu, 3 elu+1 for col<512 else identity (QKV).
// ---------------------------------------------------------------------------
template <int ACT>
__global__ __launch_bounds__(256) void gemm_bf16(const ushort* __restrict__ A, int lda,
                                                 const ushort* __restrict__ Bt,
                                                 ushort* __restrict__ Cb,
                                                 int N, int K) {
    __shared__ ushort As[4096];  // [128][32]
    __shared__ ushort Bs[4096];  // [128][32]
    int tid = threadIdx.x;
    int m0 = blockIdx.x * 128, n0 = blockIdx.y * 128;
    int wave = tid >> 6, lane = tid & 63;
    int wm = (wave >> 1) * 64, wn = (wave & 1) * 64;
    int fm = lane & 15, kg = lane >> 4;

    f32x4 acc[4][4] = {};

    for (int k0 = 0; k0 < K; k0 += 32) {
        const ushort* Ag = A + (size_t)m0 * lda + k0;
        const ushort* Bg = Bt + (size_t)n0 * K + k0;
#pragma unroll
        for (int iss = 0; iss < 2; ++iss) {
            int slot = iss * 256 + tid;
            int rr = slot >> 2, cc = (slot & 3) * 8;
            __builtin_amdgcn_global_load_lds(
                (const __attribute__((address_space(1))) void*)(Ag + (size_t)rr * lda + cc),
                (__attribute__((address_space(3))) void*)(As + iss * 2048 + wave * 512),
                16, 0, 0);
            __builtin_amdgcn_global_load_lds(
                (const __attribute__((address_space(1))) void*)(Bg + (size_t)rr * K + cc),
                (__attribute__((address_space(3))) void*)(Bs + iss * 2048 + wave * 512),
                16, 0, 0);
        }
        __syncthreads();
        bf16x8 afr[4], bfr[4];
#pragma unroll
        for (int i = 0; i < 4; ++i)
            afr[i] = *(const bf16x8*)(As + (wm + i * 16 + fm) * 32 + kg * 8);
#pragma unroll
        for (int j = 0; j < 4; ++j)
            bfr[j] = *(const bf16x8*)(Bs + (wn + j * 16 + fm) * 32 + kg * 8);
#pragma unroll
        for (int i = 0; i < 4; ++i)
#pragma unroll
            for (int j = 0; j < 4; ++j)
                acc[i][j] = __builtin_amdgcn_mfma_f32_16x16x32_bf16(afr[i], bfr[j], acc[i][j], 0, 0, 0);
        __syncthreads();
    }

#pragma unroll
    for (int i = 0; i < 4; ++i) {
        int grow0 = m0 + wm + i * 16 + kg * 4;
#pragma unroll
        for (int r = 0; r < 4; ++r) {
            size_t rowoff = (size_t)(grow0 + r) * N;
#pragma unroll
            for (int j = 0; j < 4; ++j) {
                float v = acc[i][j][r];
                int col = n0 + wn + j * 16 + fm;
                if (ACT == 2) v = fmaxf(v, 0.f);
                if (ACT == 3) v = (col < 512) ? elu1(v) : v;
                Cb[rowoff + col] = f2bf(v);
            }
        }
    }
}

// ---------------------------------------------------------------------------
// Fused GEMM + LayerNorm (round-3 proven config): T = A @ Bt^T (N=256 full
// width); per-row LN over 256. 128x256 tile, 512 threads = 8 waves (2x4).
// RES=0 (LN1):  XC[row*512 + 256 + col] = bf16(LN(T))
// RES=1 (LN2):  X[row][col] += LN(T); XC[row*512 + col] = bf16(X)
// ---------------------------------------------------------------------------
template <int RES>
__global__ __launch_bounds__(512) void gemm_ln(const ushort* __restrict__ A, int lda,
                                               const ushort* __restrict__ Bt, int K,
                                               const float* __restrict__ g,
                                               const float* __restrict__ bta,
                                               float* __restrict__ X,
                                               ushort* __restrict__ XC) {
    __shared__ ushort As[4096];   // [128][32]
    __shared__ ushort Bs[8192];   // [256][32]
    __shared__ float red[128 * 8];
    __shared__ float musig[128 * 2];
    int tid = threadIdx.x;
    int m0 = blockIdx.x * 128;
    int wave = tid >> 6, lane = tid & 63;
    int wr = wave >> 2, wc = wave & 3;
    int fm = lane & 15, kg = lane >> 4;

    f32x4 acc[4][4] = {};

    for (int k0 = 0; k0 < K; k0 += 32) {
        const ushort* Ag = A + (size_t)m0 * lda + k0;
        const ushort* Bg = Bt + k0;
        {
            int rr = tid >> 2, cc = (tid & 3) * 8;
            __builtin_amdgcn_global_load_lds(
                (const __attribute__((address_space(1))) void*)(Ag + (size_t)rr * lda + cc),
                (__attribute__((address_space(3))) void*)(As + wave * 512),
                16, 0, 0);
        }
#pragma unroll
        for (int iss = 0; iss < 2; ++iss) {
            int slot = iss * 512 + tid;
            int rr = slot >> 2, cc = (slot & 3) * 8;
            __builtin_amdgcn_global_load_lds(
                (const __attribute__((address_space(1))) void*)(Bg + (size_t)rr * K + cc),
                (__attribute__((address_space(3))) void*)(Bs + iss * 4096 + wave * 512),
                16, 0, 0);
        }
        __syncthreads();
        bf16x8 afr[4], bfr[4];
#pragma unroll
        for (int i = 0; i < 4; ++i)
            afr[i] = *(const bf16x8*)(As + (wr * 64 + i * 16 + fm) * 32 + kg * 8);
#pragma unroll
        for (int j = 0; j < 4; ++j)
            bfr[j] = *(const bf16x8*)(Bs + (wc * 64 + j * 16 + fm) * 32 + kg * 8);
#pragma unroll
        for (int i = 0; i < 4; ++i)
#pragma unroll
            for (int j = 0; j < 4; ++j)
                acc[i][j] = __builtin_amdgcn_mfma_f32_16x16x32_bf16(afr[i], bfr[j], acc[i][j], 0, 0, 0);
        __syncthreads();
    }

    // per-row partial sums (this wave covers 64 of the 256 cols)
#pragma unroll
    for (int i = 0; i < 4; ++i) {
#pragma unroll
        for (int r = 0; r < 4; ++r) {
            float s = acc[i][0][r] + acc[i][1][r] + acc[i][2][r] + acc[i][3][r];
            float q = acc[i][0][r] * acc[i][0][r] + acc[i][1][r] * acc[i][1][r] +
                      acc[i][2][r] * acc[i][2][r] + acc[i][3][r] * acc[i][3][r];
#pragma unroll
            for (int o = 1; o < 16; o <<= 1) {
                s += __shfl_xor(s, o, 64);
                q += __shfl_xor(q, o, 64);
            }
            if ((lane & 15) == 0) {
                int row = wr * 64 + i * 16 + kg * 4 + r;
                red[row * 8 + wc] = s;
                red[row * 8 + 4 + wc] = q;
            }
        }
    }
    __syncthreads();
    if (tid < 128) {
        float s = red[tid * 8 + 0] + red[tid * 8 + 1] + red[tid * 8 + 2] + red[tid * 8 + 3];
        float q = red[tid * 8 + 4] + red[tid * 8 + 5] + red[tid * 8 + 6] + red[tid * 8 + 7];
        float mu = s * (1.f / 256.f);
        float var = q * (1.f / 256.f) - mu * mu;
        musig[tid * 2] = mu;
        musig[tid * 2 + 1] = rsqrtf(var + 1e-5f);
    }
    __syncthreads();

    float gv[4], bv[4];
#pragma unroll
    for (int j = 0; j < 4; ++j) {
        int col = wc * 64 + j * 16 + fm;
        gv[j] = g[col];
        bv[j] = bta[col];
    }
#pragma unroll
    for (int i = 0; i < 4; ++i) {
#pragma unroll
        for (int r = 0; r < 4; ++r) {
            int rl = wr * 64 + i * 16 + kg * 4 + r;
            float mu = musig[rl * 2], rstd = musig[rl * 2 + 1];
            size_t grow = (size_t)(m0 + rl);
#pragma unroll
            for (int j = 0; j < 4; ++j) {
                int col = wc * 64 + j * 16 + fm;
                float v = (acc[i][j][r] - mu) * rstd * gv[j] + bv[j];
                if (RES) {
                    float x = X[grow * 256 + col] + v;
                    X[grow * 256 + col] = x;
                    XC[grow * 512 + col] = f2bf(x);
                } else {
                    XC[grow * 512 + 256 + col] = f2bf(v);
                }
            }
        }
    }
}

// ---------------------------------------------------------------------------
// KV partials, LDS-free register-blocked:
//   thread (sg, d2, v2): 4x4 (d,v) block, s in [sp*512 + sg*128, +128)
//   KVp[sp*64+bh][d][v], KSp[sp*64+bh][d]. Per s a wave reads 2x64B lines.
// ---------------------------------------------------------------------------
__global__ __launch_bounds__(256) void kv_kernel(const ushort* __restrict__ Kf,
                                                 const ushort* __restrict__ Vf,
                                                 int str,
                                                 float* __restrict__ KVp,
                                                 float* __restrict__ KSp) {
    __shared__ float redv[3][8][8][16];  // 12 KB
    __shared__ float redk[3][8][4];
    int tid = threadIdx.x;
    int bh = blockIdx.x, sp = blockIdx.y;
    int b = bh >> 3, h = bh & 7;
    int sg = tid >> 6, d2 = (tid >> 3) & 7, v2 = tid & 7;
    size_t rbase = (size_t)(b * LTOT + sp * 512 + sg * 128) * str;
    const ushort* Kp = Kf + rbase + h * 32 + d2 * 4;
    const ushort* Vp = Vf + rbase + h * 32 + v2 * 4;
    float acc[4][4] = {};
    float ks[4] = {};
#pragma unroll 4
    for (int s = 0; s < 128; ++s) {
        ushort4 k4 = *(const ushort4*)(Kp + (size_t)s * str);
        ushort4 v4 = *(const ushort4*)(Vp + (size_t)s * str);
        float kk0 = b2f(k4.x), kk1 = b2f(k4.y), kk2 = b2f(k4.z), kk3 = b2f(k4.w);
        float vv0 = b2f(v4.x), vv1 = b2f(v4.y), vv2 = b2f(v4.z), vv3 = b2f(v4.w);
        acc[0][0] += kk0 * vv0; acc[0][1] += kk0 * vv1; acc[0][2] += kk0 * vv2; acc[0][3] += kk0 * vv3;
        acc[1][0] += kk1 * vv0; acc[1][1] += kk1 * vv1; acc[1][2] += kk1 * vv2; acc[1][3] += kk1 * vv3;
        acc[2][0] += kk2 * vv0; acc[2][1] += kk2 * vv1; acc[2][2] += kk2 * vv2; acc[2][3] += kk2 * vv3;
        acc[3][0] += kk3 * vv0; acc[3][1] += kk3 * vv1; acc[3][2] += kk3 * vv2; acc[3][3] += kk3 * vv3;
        ks[0] += kk0; ks[1] += kk1; ks[2] += kk2; ks[3] += kk3;
    }
    if (sg > 0) {
#pragma unroll
        for (int i = 0; i < 4; ++i)
#pragma unroll
            for (int j = 0; j < 4; ++j)
                redv[sg - 1][d2][v2][i * 4 + j] = acc[i][j];
        if (v2 == 0) {
#pragma unroll
            for (int i = 0; i < 4; ++i) redk[sg - 1][d2][i] = ks[i];
        }
    }
    __syncthreads();
    if (sg == 0) {
#pragma unroll
        for (int t = 0; t < 3; ++t)
#pragma unroll
            for (int i = 0; i < 4; ++i)
#pragma unroll
                for (int j = 0; j < 4; ++j)
                    acc[i][j] += redv[t][d2][v2][i * 4 + j];
        float* base = KVp + (size_t)(sp * 64 + bh) * 1024;
#pragma unroll
        for (int i = 0; i < 4; ++i) {
            float4 o = make_float4(acc[i][0], acc[i][1], acc[i][2], acc[i][3]);
            *(float4*)(base + (d2 * 4 + i) * 32 + v2 * 4) = o;
        }
        if (v2 == 0) {
#pragma unroll
            for (int t = 0; t < 3; ++t)
#pragma unroll
                for (int i = 0; i < 4; ++i) ks[i] += redk[t][d2][i];
#pragma unroll
            for (int i = 0; i < 4; ++i)
                KSp[(sp * 64 + bh) * 32 + d2 * 4 + i] = ks[i];
        }
    }
}

// ---------------------------------------------------------------------------
// msg[b,l,h,v] = (sum_d Q*KV) / (sum_d Q*KS + eps); Q bf16 stride qstr.
// Reduces the 8 sp-partials of KVp/KSp inline while staging to LDS.
// ---------------------------------------------------------------------------
__global__ __launch_bounds__(256) void msg_kernel(const ushort* __restrict__ Qb, int qstr,
                                                  const float* __restrict__ KVp,
                                                  const float* __restrict__ KSp,
                                                  ushort* __restrict__ Msgb) {
    __shared__ float KVs[8 * 1032];
    __shared__ float KSs[256];
    int tid = threadIdx.x;
    int b = blockIdx.y;
    int l0 = blockIdx.x * 32;
    for (int i = tid; i < 8192; i += 256) {
        int h = i >> 10, r = i & 1023;
        float s = 0.f;
#pragma unroll
        for (int sp = 0; sp < 8; ++sp)
            s += KVp[((size_t)(sp * 64 + b * 8 + h)) * 1024 + r];
        KVs[h * 1032 + r] = s;
    }
    {
        float s = 0.f;
        int h = tid >> 5, d = tid & 31;
#pragma unroll
        for (int sp = 0; sp < 8; ++sp)
            s += KSp[(sp * 64 + b * 8 + h) * 32 + d];
        KSs[tid] = s;
    }
    __syncthreads();
    int l = l0 + (tid >> 3);
    int h = tid & 7;
    const ushort* qp = Qb + ((size_t)(b * LTOT + l)) * qstr + h * 32;
    float qv[32];
#pragma unroll
    for (int i = 0; i < 8; ++i) {
        ushort4 q4 = *(const ushort4*)(qp + i * 4);
        qv[i * 4 + 0] = b2f(q4.x); qv[i * 4 + 1] = b2f(q4.y);
        qv[i * 4 + 2] = b2f(q4.z); qv[i * 4 + 3] = b2f(q4.w);
    }
    float den = 1e-6f;
#pragma unroll
    for (int d2 = 0; d2 < 32; ++d2) den += qv[d2] * KSs[h * 32 + d2];
    float rz = 1.f / den;
    float acc[32] = {};
#pragma unroll
    for (int d2 = 0; d2 < 32; ++d2) {
        float qd = qv[d2];
        const float* kvp = &KVs[h * 1032 + d2 * 32];
#pragma unroll
        for (int v = 0; v < 32; ++v) acc[v] += qd * kvp[v];
    }
    ushort* op = Msgb + ((size_t)(b * LTOT + l)) * DM + h * 32;
#pragma unroll
    for (int i = 0; i < 4; ++i) {
        uint2 p;
        p.x = pkbf(acc[i * 8 + 0] * rz, acc[i * 8 + 1] * rz);
        p.y = pkbf(acc[i * 8 + 2] * rz, acc[i * 8 + 3] * rz);
        uint2 p2;
        p2.x = pkbf(acc[i * 8 + 4] * rz, acc[i * 8 + 5] * rz);
        p2.y = pkbf(acc[i * 8 + 6] * rz, acc[i * 8 + 7] * rz);
        *(uint2*)(op + i * 8) = p;
        *(uint2*)(op + i * 8 + 4) = p2;
    }
}

// ---------------------------------------------------------------------------
// Orchestration
// ---------------------------------------------------------------------------
extern "C" void kernel_launch(void* const* d_in, const int* in_sizes, int n_in,
                              void* d_out, int out_size, void* d_ws, size_t ws_size,
                              hipStream_t stream) {
    const float* feats = (const float*)d_in[0];
    const float* Wq = (const float*)d_in[1];
    const float* Wk = (const float*)d_in[2];
    const float* Wv = (const float*)d_in[3];
    const float* Wm = (const float*)d_in[4];
    const float* W1 = (const float*)d_in[5];
    const float* W2 = (const float*)d_in[6];
    const float* g1 = (const float*)d_in[7];
    const float* b1 = (const float*)d_in[8];
    const float* g2 = (const float*)d_in[9];
    const float* b2 = (const float*)d_in[10];

    float* ws = (float*)d_ws;
    float* X = ws;                            // fp32 residual [32768][256]
    ushort* XC = (ushort*)(ws + NX);          // bf16 [32768][512]: [x | LN1(msg)]
    ushort* QKVb = (ushort*)(ws + 2 * NX);    // bf16 [32768][768]; aliased by HBb
    ushort* HBb = QKVb;                       // bf16 [32768][512] MLP hidden

    // d_out doubles as scratch until the final unprep (32 MB)
    float* dout = (float*)d_out;
    ushort* msgb = (ushort*)dout;             // bf16 [32768][256] (16 MB)
    ushort* WB = (ushort*)dout + NX;
    ushort* WTqkv = WB;                       // [4][768][256]
    ushort* WTm = WB + 4 * 196608;            // [4][256][256]
    ushort* WT1 = WTm + 4 * 65536;            // [4][512][512]
    ushort* WT2 = WT1 + 4 * 262144;           // [4][256][512]
    float* KVp = dout + (NX + 2621440) / 2;   // [8][64][1024]
    float* KSp = KVp + 524288;                // [8][64][32]

    wtrans_all<<<2560, 256, 0, stream>>>(Wq, Wk, Wv, Wm, W1, W2, WTqkv, WTm, WT1, WT2);
    prep_kernel<<<dim3(128, 8, 8), dim3(32, 8), 0, stream>>>(feats, X, XC);

    for (int layer = 0; layer < 4; ++layer) {
        const ushort* wtqkv = WTqkv + (size_t)layer * 196608;
        const ushort* wtm = WTm + (size_t)layer * 65536;
        const ushort* wt1 = WT1 + (size_t)layer * 262144;
        const ushort* wt2 = WT2 + (size_t)layer * 131072;
        const float* lg1 = g1 + layer * DM;
        const float* lb1 = b1 + layer * DM;
        const float* lg2 = g2 + layer * DM;
        const float* lb2 = b2 + layer * DM;

        // QKV fused: [32768][768] = elu1/elu1/id( XC[:, :256] @ [Wq|Wk|Wv] )
        gemm_bf16<3><<<dim3(256, 6), 256, 0, stream>>>(XC, 512, wtqkv, QKVb, 768, 256);
        kv_kernel<<<dim3(64, 8), 256, 0, stream>>>(QKVb + 256, QKVb + 512, 768, KVp, KSp);
        msg_kernel<<<dim3(128, 8), 256, 0, stream>>>(QKVb, 768, KVp, KSp, msgb);
        // Wm GEMM + LN1 fused -> XC right half
        gemm_ln<0><<<256, 512, 0, stream>>>(msgb, 256, wtm, 256, lg1, lb1, nullptr, XC);
        // MLP1: relu( XC[:, :512] @ W1 ) -> HBb  (aliases QKVb, which is dead)
        gemm_bf16<2><<<dim3(256, 4), 256, 0, stream>>>(XC, 512, wt1, HBb, 512, 512);
        // MLP2 + LN2 + residual fused -> X, XC left half
        gemm_ln<1><<<256, 512, 0, stream>>>(HBb, 512, wt2, 512, lg2, lb2, X, XC);
    }

    unprep_kernel<<<dim3(128, 8, 8), dim3(32, 8), 0, stream>>>(X, dout);
}

// Round 6
// 782.816 us; speedup vs baseline: 1.1513x; 1.1513x over previous
//
#include <hip/hip_runtime.h>
#include <hip/hip_bf16.h>

#define LTOT 4096
#define DM 256
#define BATCH 8
#define MROWS (BATCH * LTOT)     // 32768
#define NX ((size_t)MROWS * DM)  // 8388608 elements

typedef __bf16 bf16x8 __attribute__((ext_vector_type(8)));
typedef float f32x4 __attribute__((ext_vector_type(4)));

__device__ __forceinline__ float elu1(float x) {
    return x > 0.f ? x + 1.f : expf(x);
}
__device__ __forceinline__ ushort f2bf(float f) {
    unsigned u = __float_as_uint(f);
    u += 0x7FFFu + ((u >> 16) & 1u);
    return (ushort)(u >> 16);
}
__device__ __forceinline__ unsigned pkbf(float a, float b) {
    return (unsigned)f2bf(a) | ((unsigned)f2bf(b) << 16);
}
__device__ __forceinline__ float b2f(ushort u) {
    return __uint_as_float(((unsigned)u) << 16);
}

// ---------------------------------------------------------------------------
// prep: X[b,l,c] = feats[b,c,l] + pos(c,l) (fp32); XC left half = bf16(same)
// ---------------------------------------------------------------------------
__global__ __launch_bounds__(256) void prep_kernel(const float* __restrict__ feats,
                                                   float* __restrict__ X,
                                                   ushort* __restrict__ XC) {
    __shared__ float tile[32][33];
    int b = blockIdx.z;
    int l0 = blockIdx.x * 32;
    int c0 = blockIdx.y * 32;
    int tx = threadIdx.x, ty = threadIdx.y;
#pragma unroll
    for (int j = 0; j < 4; ++j) {
        int c = c0 + ty + j * 8;
        tile[ty + j * 8][tx] = feats[((size_t)(b * DM + c)) * LTOT + l0 + tx];
    }
    __syncthreads();
#pragma unroll
    for (int j = 0; j < 4; ++j) {
        int l = l0 + ty + j * 8;
        int c = c0 + tx;
        int i2 = (c >> 2) * 2;
        float dv = expf((float)i2 * -0.07195578415156063f);
        int rem = c & 3;
        int y = l >> 6, xc = l & 63;
        float pos = (rem < 2) ? (float)(xc + 1) : (float)(y + 1);
        float arg = pos * dv;
        float pe = (rem & 1) ? cosf(arg) : sinf(arg);
        float val = tile[tx][ty + j * 8] + pe;
        size_t row = (size_t)(b * LTOT + l);
        X[row * DM + c] = val;
        XC[row * 512 + c] = f2bf(val);
    }
}

__global__ __launch_bounds__(256) void unprep_kernel(const float* __restrict__ X,
                                                     float* __restrict__ out) {
    __shared__ float tile[32][33];
    int b = blockIdx.z;
    int l0 = blockIdx.x * 32;
    int c0 = blockIdx.y * 32;
    int tx = threadIdx.x, ty = threadIdx.y;
#pragma unroll
    for (int j = 0; j < 4; ++j) {
        int l = l0 + ty + j * 8;
        tile[ty + j * 8][tx] = X[((size_t)(b * LTOT + l)) * DM + c0 + tx];
    }
    __syncthreads();
#pragma unroll
    for (int j = 0; j < 4; ++j) {
        int c = c0 + ty + j * 8;
        out[((size_t)(b * DM + c)) * LTOT + l0 + tx] = tile[tx][ty + j * 8];
    }
}

// ---------------------------------------------------------------------------
// ALL weight transposes in one dispatch. blockIdx.x routes:
// [0,256)Wq [256,512)Wk [512,768)Wv [768,1024)Wm [1024,2048)W1 [2048,2560)W2
// ---------------------------------------------------------------------------
__global__ __launch_bounds__(256) void wtrans_all(const float* __restrict__ Wq,
                                                  const float* __restrict__ Wk,
                                                  const float* __restrict__ Wv,
                                                  const float* __restrict__ Wm,
                                                  const float* __restrict__ W1,
                                                  const float* __restrict__ W2,
                                                  ushort* __restrict__ WTqkv,
                                                  ushort* __restrict__ WTm,
                                                  ushort* __restrict__ WT1,
                                                  ushort* __restrict__ WT2) {
    __shared__ float t[32][33];
    int idx = blockIdx.x;
    const float* W;
    ushort* WT;
    int K, N, KT, z, r;
    size_t in_ls, out_ls;
    if (idx < 1024) {
        int which = idx >> 8, local = idx & 255;
        K = 256; N = 256; KT = 8; in_ls = 65536;
        if (which == 0)      { W = Wq; WT = WTqkv;          out_ls = 196608; }
        else if (which == 1) { W = Wk; WT = WTqkv + 65536;  out_ls = 196608; }
        else if (which == 2) { W = Wv; WT = WTqkv + 131072; out_ls = 196608; }
        else                 { W = Wm; WT = WTm;            out_ls = 65536; }
        z = local >> 6; r = local & 63;
    } else if (idx < 2048) {
        int local = idx - 1024;
        K = 512; N = 512; KT = 16; in_ls = 262144; out_ls = 262144;
        W = W1; WT = WT1;
        z = local >> 8; r = local & 255;
    } else {
        int local = idx - 2048;
        K = 512; N = 256; KT = 16; in_ls = 131072; out_ls = 131072;
        W = W2; WT = WT2;
        z = local >> 7; r = local & 127;
    }
    int k0 = (r % KT) * 32, n0 = (r / KT) * 32;
    const float* Wz = W + (size_t)z * in_ls;
    ushort* WTz = WT + (size_t)z * out_ls;
    int tx = threadIdx.x & 31, ty = threadIdx.x >> 5;
#pragma unroll
    for (int j = 0; j < 4; ++j)
        t[ty + j * 8][tx] = Wz[(size_t)(k0 + ty + j * 8) * N + n0 + tx];
    __syncthreads();
#pragma unroll
    for (int j = 0; j < 4; ++j)
        WTz[(size_t)(n0 + ty + j * 8) * K + k0 + tx] = f2bf(t[tx][ty + j * 8]);
}

// ---------------------------------------------------------------------------
// bf16 MFMA GEMM (round-3 proven config): Cb[M,N] = act(A[M,K] @ Bt[N,K]^T)
// 128x128 tile, BK=32, 4 waves 2x2, 4x4 frags of 16x16x32.
// ACT: 2 relu, 3 elu+1 for col<512 else identity (QKV).
// ---------------------------------------------------------------------------
template <int ACT>
__global__ __launch_bounds__(256) void gemm_bf16(const ushort* __restrict__ A, int lda,
                                                 const ushort* __restrict__ Bt,
                                                 ushort* __restrict__ Cb,
                                                 int N, int K) {
    __shared__ ushort As[4096];  // [128][32]
    __shared__ ushort Bs[4096];  // [128][32]
    int tid = threadIdx.x;
    int m0 = blockIdx.x * 128, n0 = blockIdx.y * 128;
    int wave = tid >> 6, lane = tid & 63;
    int wm = (wave >> 1) * 64, wn = (wave & 1) * 64;
    int fm = lane & 15, kg = lane >> 4;

    f32x4 acc[4][4] = {};

    for (int k0 = 0; k0 < K; k0 += 32) {
        const ushort* Ag = A + (size_t)m0 * lda + k0;
        const ushort* Bg = Bt + (size_t)n0 * K + k0;
#pragma unroll
        for (int iss = 0; iss < 2; ++iss) {
            int slot = iss * 256 + tid;
            int rr = slot >> 2, cc = (slot & 3) * 8;
            __builtin_amdgcn_global_load_lds(
                (const __attribute__((address_space(1))) void*)(Ag + (size_t)rr * lda + cc),
                (__attribute__((address_space(3))) void*)(As + iss * 2048 + wave * 512),
                16, 0, 0);
            __builtin_amdgcn_global_load_lds(
                (const __attribute__((address_space(1))) void*)(Bg + (size_t)rr * K + cc),
                (__attribute__((address_space(3))) void*)(Bs + iss * 2048 + wave * 512),
                16, 0, 0);
        }
        __syncthreads();
        bf16x8 afr[4], bfr[4];
#pragma unroll
        for (int i = 0; i < 4; ++i)
            afr[i] = *(const bf16x8*)(As + (wm + i * 16 + fm) * 32 + kg * 8);
#pragma unroll
        for (int j = 0; j < 4; ++j)
            bfr[j] = *(const bf16x8*)(Bs + (wn + j * 16 + fm) * 32 + kg * 8);
#pragma unroll
        for (int i = 0; i < 4; ++i)
#pragma unroll
            for (int j = 0; j < 4; ++j)
                acc[i][j] = __builtin_amdgcn_mfma_f32_16x16x32_bf16(afr[i], bfr[j], acc[i][j], 0, 0, 0);
        __syncthreads();
    }

#pragma unroll
    for (int i = 0; i < 4; ++i) {
        int grow0 = m0 + wm + i * 16 + kg * 4;
#pragma unroll
        for (int r = 0; r < 4; ++r) {
            size_t rowoff = (size_t)(grow0 + r) * N;
#pragma unroll
            for (int j = 0; j < 4; ++j) {
                float v = acc[i][j][r];
                int col = n0 + wn + j * 16 + fm;
                if (ACT == 2) v = fmaxf(v, 0.f);
                if (ACT == 3) v = (col < 512) ? elu1(v) : v;
                Cb[rowoff + col] = f2bf(v);
            }
        }
    }
}

// ---------------------------------------------------------------------------
// Fused GEMM + LayerNorm (round-3 proven config): T = A @ Bt^T (N=256 full
// width); per-row LN over 256. 128x256 tile, 512 threads = 8 waves (2x4).
// RES=0 (LN1):  XC[row*512 + 256 + col] = bf16(LN(T))
// RES=1 (LN2):  X[row][col] += LN(T); XC[row*512 + col] = bf16(X)
// ---------------------------------------------------------------------------
template <int RES>
__global__ __launch_bounds__(512) void gemm_ln(const ushort* __restrict__ A, int lda,
                                               const ushort* __restrict__ Bt, int K,
                                               const float* __restrict__ g,
                                               const float* __restrict__ bta,
                                               float* __restrict__ X,
                                               ushort* __restrict__ XC) {
    __shared__ ushort As[4096];   // [128][32]
    __shared__ ushort Bs[8192];   // [256][32]
    __shared__ float red[128 * 8];
    __shared__ float musig[128 * 2];
    int tid = threadIdx.x;
    int m0 = blockIdx.x * 128;
    int wave = tid >> 6, lane = tid & 63;
    int wr = wave >> 2, wc = wave & 3;
    int fm = lane & 15, kg = lane >> 4;

    f32x4 acc[4][4] = {};

    for (int k0 = 0; k0 < K; k0 += 32) {
        const ushort* Ag = A + (size_t)m0 * lda + k0;
        const ushort* Bg = Bt + k0;
        {
            int rr = tid >> 2, cc = (tid & 3) * 8;
            __builtin_amdgcn_global_load_lds(
                (const __attribute__((address_space(1))) void*)(Ag + (size_t)rr * lda + cc),
                (__attribute__((address_space(3))) void*)(As + wave * 512),
                16, 0, 0);
        }
#pragma unroll
        for (int iss = 0; iss < 2; ++iss) {
            int slot = iss * 512 + tid;
            int rr = slot >> 2, cc = (slot & 3) * 8;
            __builtin_amdgcn_global_load_lds(
                (const __attribute__((address_space(1))) void*)(Bg + (size_t)rr * K + cc),
                (__attribute__((address_space(3))) void*)(Bs + iss * 4096 + wave * 512),
                16, 0, 0);
        }
        __syncthreads();
        bf16x8 afr[4], bfr[4];
#pragma unroll
        for (int i = 0; i < 4; ++i)
            afr[i] = *(const bf16x8*)(As + (wr * 64 + i * 16 + fm) * 32 + kg * 8);
#pragma unroll
        for (int j = 0; j < 4; ++j)
            bfr[j] = *(const bf16x8*)(Bs + (wc * 64 + j * 16 + fm) * 32 + kg * 8);
#pragma unroll
        for (int i = 0; i < 4; ++i)
#pragma unroll
            for (int j = 0; j < 4; ++j)
                acc[i][j] = __builtin_amdgcn_mfma_f32_16x16x32_bf16(afr[i], bfr[j], acc[i][j], 0, 0, 0);
        __syncthreads();
    }

    // per-row partial sums (this wave covers 64 of the 256 cols)
#pragma unroll
    for (int i = 0; i < 4; ++i) {
#pragma unroll
        for (int r = 0; r < 4; ++r) {
            float s = acc[i][0][r] + acc[i][1][r] + acc[i][2][r] + acc[i][3][r];
            float q = acc[i][0][r] * acc[i][0][r] + acc[i][1][r] * acc[i][1][r] +
                      acc[i][2][r] * acc[i][2][r] + acc[i][3][r] * acc[i][3][r];
#pragma unroll
            for (int o = 1; o < 16; o <<= 1) {
                s += __shfl_xor(s, o, 64);
                q += __shfl_xor(q, o, 64);
            }
            if ((lane & 15) == 0) {
                int row = wr * 64 + i * 16 + kg * 4 + r;
                red[row * 8 + wc] = s;
                red[row * 8 + 4 + wc] = q;
            }
        }
    }
    __syncthreads();
    if (tid < 128) {
        float s = red[tid * 8 + 0] + red[tid * 8 + 1] + red[tid * 8 + 2] + red[tid * 8 + 3];
        float q = red[tid * 8 + 4] + red[tid * 8 + 5] + red[tid * 8 + 6] + red[tid * 8 + 7];
        float mu = s * (1.f / 256.f);
        float var = q * (1.f / 256.f) - mu * mu;
        musig[tid * 2] = mu;
        musig[tid * 2 + 1] = rsqrtf(var + 1e-5f);
    }
    __syncthreads();

    float gv[4], bv[4];
#pragma unroll
    for (int j = 0; j < 4; ++j) {
        int col = wc * 64 + j * 16 + fm;
        gv[j] = g[col];
        bv[j] = bta[col];
    }
#pragma unroll
    for (int i = 0; i < 4; ++i) {
#pragma unroll
        for (int r = 0; r < 4; ++r) {
            int rl = wr * 64 + i * 16 + kg * 4 + r;
            float mu = musig[rl * 2], rstd = musig[rl * 2 + 1];
            size_t grow = (size_t)(m0 + rl);
#pragma unroll
            for (int j = 0; j < 4; ++j) {
                int col = wc * 64 + j * 16 + fm;
                float v = (acc[i][j][r] - mu) * rstd * gv[j] + bv[j];
                if (RES) {
                    float x = X[grow * 256 + col] + v;
                    X[grow * 256 + col] = x;
                    XC[grow * 512 + col] = f2bf(x);
                } else {
                    XC[grow * 512 + 256 + col] = f2bf(v);
                }
            }
        }
    }
}

// ---------------------------------------------------------------------------
// KV partials, LDS-free register-blocked:
//   thread (sg, d2, v2): 4x4 (d,v) block, s in [sp*512 + sg*128, +128)
//   KVp[sp*64+bh][d][v], KSp[sp*64+bh][d]. Per s a wave reads 2x64B lines.
// ---------------------------------------------------------------------------
__global__ __launch_bounds__(256) void kv_kernel(const ushort* __restrict__ Kf,
                                                 const ushort* __restrict__ Vf,
                                                 int str,
                                                 float* __restrict__ KVp,
                                                 float* __restrict__ KSp) {
    __shared__ float redv[3][8][8][16];  // 12 KB
    __shared__ float redk[3][8][4];
    int tid = threadIdx.x;
    int bh = blockIdx.x, sp = blockIdx.y;
    int b = bh >> 3, h = bh & 7;
    int sg = tid >> 6, d2 = (tid >> 3) & 7, v2 = tid & 7;
    size_t rbase = (size_t)(b * LTOT + sp * 512 + sg * 128) * str;
    const ushort* Kp = Kf + rbase + h * 32 + d2 * 4;
    const ushort* Vp = Vf + rbase + h * 32 + v2 * 4;
    float acc[4][4] = {};
    float ks[4] = {};
#pragma unroll 4
    for (int s = 0; s < 128; ++s) {
        ushort4 k4 = *(const ushort4*)(Kp + (size_t)s * str);
        ushort4 v4 = *(const ushort4*)(Vp + (size_t)s * str);
        float kk0 = b2f(k4.x), kk1 = b2f(k4.y), kk2 = b2f(k4.z), kk3 = b2f(k4.w);
        float vv0 = b2f(v4.x), vv1 = b2f(v4.y), vv2 = b2f(v4.z), vv3 = b2f(v4.w);
        acc[0][0] += kk0 * vv0; acc[0][1] += kk0 * vv1; acc[0][2] += kk0 * vv2; acc[0][3] += kk0 * vv3;
        acc[1][0] += kk1 * vv0; acc[1][1] += kk1 * vv1; acc[1][2] += kk1 * vv2; acc[1][3] += kk1 * vv3;
        acc[2][0] += kk2 * vv0; acc[2][1] += kk2 * vv1; acc[2][2] += kk2 * vv2; acc[2][3] += kk2 * vv3;
        acc[3][0] += kk3 * vv0; acc[3][1] += kk3 * vv1; acc[3][2] += kk3 * vv2; acc[3][3] += kk3 * vv3;
        ks[0] += kk0; ks[1] += kk1; ks[2] += kk2; ks[3] += kk3;
    }
    if (sg > 0) {
#pragma unroll
        for (int i = 0; i < 4; ++i)
#pragma unroll
            for (int j = 0; j < 4; ++j)
                redv[sg - 1][d2][v2][i * 4 + j] = acc[i][j];
        if (v2 == 0) {
#pragma unroll
            for (int i = 0; i < 4; ++i) redk[sg - 1][d2][i] = ks[i];
        }
    }
    __syncthreads();
    if (sg == 0) {
#pragma unroll
        for (int t = 0; t < 3; ++t)
#pragma unroll
            for (int i = 0; i < 4; ++i)
#pragma unroll
                for (int j = 0; j < 4; ++j)
                    acc[i][j] += redv[t][d2][v2][i * 4 + j];
        float* base = KVp + (size_t)(sp * 64 + bh) * 1024;
#pragma unroll
        for (int i = 0; i < 4; ++i) {
            float4 o = make_float4(acc[i][0], acc[i][1], acc[i][2], acc[i][3]);
            *(float4*)(base + (d2 * 4 + i) * 32 + v2 * 4) = o;
        }
        if (v2 == 0) {
#pragma unroll
            for (int t = 0; t < 3; ++t)
#pragma unroll
                for (int i = 0; i < 4; ++i) ks[i] += redk[t][d2][i];
#pragma unroll
            for (int i = 0; i < 4; ++i)
                KSp[(sp * 64 + bh) * 32 + d2 * 4 + i] = ks[i];
        }
    }
}

// ---------------------------------------------------------------------------
// reduce partials: KV[bh] = sum_sp KVp[sp][bh]; KS likewise (one dispatch)
// ---------------------------------------------------------------------------
__global__ __launch_bounds__(256) void kvreduce_kernel(const float* __restrict__ KVp,
                                                       const float* __restrict__ KSp,
                                                       float* __restrict__ KV,
                                                       float* __restrict__ KS) {
    int bh = blockIdx.x;
    int t = threadIdx.x;
    float4 s = make_float4(0.f, 0.f, 0.f, 0.f);
#pragma unroll
    for (int sp = 0; sp < 8; ++sp) {
        float4 v = *(const float4*)(KVp + ((size_t)(sp * 64 + bh)) * 1024 + t * 4);
        s.x += v.x; s.y += v.y; s.z += v.z; s.w += v.w;
    }
    *(float4*)(KV + (size_t)bh * 1024 + t * 4) = s;
    if (t < 32) {
        float ks = 0.f;
#pragma unroll
        for (int sp = 0; sp < 8; ++sp) ks += KSp[(sp * 64 + bh) * 32 + t];
        KS[bh * 32 + t] = ks;
    }
}

// ---------------------------------------------------------------------------
// msg[b,l,h,v] = (sum_d Q*KV) / (sum_d Q*KS + eps); Q bf16 stride qstr.
// Round-3 form: stages FINAL KV (32 KB) once per block.
// ---------------------------------------------------------------------------
__global__ __launch_bounds__(256) void msg_kernel(const ushort* __restrict__ Qb, int qstr,
                                                  const float* __restrict__ KV,
                                                  const float* __restrict__ KS,
                                                  ushort* __restrict__ Msgb) {
    __shared__ float KVs[8 * 1032];
    __shared__ float KSs[256];
    int tid = threadIdx.x;
    int b = blockIdx.y;
    int l0 = blockIdx.x * 32;
    for (int i = tid; i < 8192; i += 256) {
        int h = i >> 10, r = i & 1023;
        KVs[h * 1032 + r] = KV[((size_t)(b * 8 + h)) * 1024 + r];
    }
    KSs[tid] = KS[b * 256 + tid];
    __syncthreads();
    int l = l0 + (tid >> 3);
    int h = tid & 7;
    const ushort* qp = Qb + ((size_t)(b * LTOT + l)) * qstr + h * 32;
    float qv[32];
#pragma unroll
    for (int i = 0; i < 8; ++i) {
        ushort4 q4 = *(const ushort4*)(qp + i * 4);
        qv[i * 4 + 0] = b2f(q4.x); qv[i * 4 + 1] = b2f(q4.y);
        qv[i * 4 + 2] = b2f(q4.z); qv[i * 4 + 3] = b2f(q4.w);
    }
    float den = 1e-6f;
#pragma unroll
    for (int d2 = 0; d2 < 32; ++d2) den += qv[d2] * KSs[h * 32 + d2];
    float rz = 1.f / den;
    float acc[32] = {};
#pragma unroll
    for (int d2 = 0; d2 < 32; ++d2) {
        float qd = qv[d2];
        const float* kvp = &KVs[h * 1032 + d2 * 32];
#pragma unroll
        for (int v = 0; v < 32; ++v) acc[v] += qd * kvp[v];
    }
    ushort* op = Msgb + ((size_t)(b * LTOT + l)) * DM + h * 32;
#pragma unroll
    for (int i = 0; i < 4; ++i) {
        uint2 p;
        p.x = pkbf(acc[i * 8 + 0] * rz, acc[i * 8 + 1] * rz);
        p.y = pkbf(acc[i * 8 + 2] * rz, acc[i * 8 + 3] * rz);
        uint2 p2;
        p2.x = pkbf(acc[i * 8 + 4] * rz, acc[i * 8 + 5] * rz);
        p2.y = pkbf(acc[i * 8 + 6] * rz, acc[i * 8 + 7] * rz);
        *(uint2*)(op + i * 8) = p;
        *(uint2*)(op + i * 8 + 4) = p2;
    }
}

// ---------------------------------------------------------------------------
// Orchestration
// ---------------------------------------------------------------------------
extern "C" void kernel_launch(void* const* d_in, const int* in_sizes, int n_in,
                              void* d_out, int out_size, void* d_ws, size_t ws_size,
                              hipStream_t stream) {
    const float* feats = (const float*)d_in[0];
    const float* Wq = (const float*)d_in[1];
    const float* Wk = (const float*)d_in[2];
    const float* Wv = (const float*)d_in[3];
    const float* Wm = (const float*)d_in[4];
    const float* W1 = (const float*)d_in[5];
    const float* W2 = (const float*)d_in[6];
    const float* g1 = (const float*)d_in[7];
    const float* b1 = (const float*)d_in[8];
    const float* g2 = (const float*)d_in[9];
    const float* b2 = (const float*)d_in[10];

    float* ws = (float*)d_ws;
    float* X = ws;                            // fp32 residual [32768][256]
    ushort* XC = (ushort*)(ws + NX);          // bf16 [32768][512]: [x | LN1(msg)]
    ushort* QKVb = (ushort*)(ws + 2 * NX);    // bf16 [32768][768]; aliased by HBb
    ushort* HBb = QKVb;                       // bf16 [32768][512] MLP hidden

    // d_out doubles as scratch until the final unprep (32 MB)
    float* dout = (float*)d_out;
    ushort* msgb = (ushort*)dout;             // bf16 [32768][256] (16 MB)
    ushort* WB = (ushort*)dout + NX;
    ushort* WTqkv = WB;                       // [4][768][256]
    ushort* WTm = WB + 4 * 196608;            // [4][256][256]
    ushort* WT1 = WTm + 4 * 65536;            // [4][512][512]
    ushort* WT2 = WT1 + 4 * 262144;           // [4][256][512]
    float* KVp = dout + (NX + 2621440) / 2;   // [8][64][1024]
    float* KSp = KVp + 524288;                // [8][64][32]
    float* KV = KSp + 16384;                  // [64][1024]
    float* KS = KV + 65536;                   // [64][32]

    wtrans_all<<<2560, 256, 0, stream>>>(Wq, Wk, Wv, Wm, W1, W2, WTqkv, WTm, WT1, WT2);
    prep_kernel<<<dim3(128, 8, 8), dim3(32, 8), 0, stream>>>(feats, X, XC);

    for (int layer = 0; layer < 4; ++layer) {
        const ushort* wtqkv = WTqkv + (size_t)layer * 196608;
        const ushort* wtm = WTm + (size_t)layer * 65536;
        const ushort* wt1 = WT1 + (size_t)layer * 262144;
        const ushort* wt2 = WT2 + (size_t)layer * 131072;
        const float* lg1 = g1 + layer * DM;
        const float* lb1 = b1 + layer * DM;
        const float* lg2 = g2 + layer * DM;
        const float* lb2 = b2 + layer * DM;

        // QKV fused: [32768][768] = elu1/elu1/id( XC[:, :256] @ [Wq|Wk|Wv] )
        gemm_bf16<3><<<dim3(256, 6), 256, 0, stream>>>(XC, 512, wtqkv, QKVb, 768, 256);
        kv_kernel<<<dim3(64, 8), 256, 0, stream>>>(QKVb + 256, QKVb + 512, 768, KVp, KSp);
        kvreduce_kernel<<<64, 256, 0, stream>>>(KVp, KSp, KV, KS);
        msg_kernel<<<dim3(128, 8), 256, 0, stream>>>(QKVb, 768, KV, KS, msgb);
        // Wm GEMM + LN1 fused -> XC right half
        gemm_ln<0><<<256, 512, 0, stream>>>(msgb, 256, wtm, 256, lg1, lb1, nullptr, XC);
        // MLP1: relu( XC[:, :512] @ W1 ) -> HBb  (aliases QKVb, which is dead)
        gemm_bf16<2><<<dim3(256, 4), 256, 0, stream>>>(XC, 512, wt1, HBb, 512, 512);
        // MLP2 + LN2 + residual fused -> X, XC left half
        gemm_ln<1><<<256, 512, 0, stream>>>(HBb, 512, wt2, 512, lg2, lb2, X, XC);
    }

    unprep_kernel<<<dim3(128, 8, 8), dim3(32, 8), 0, stream>>>(X, dout);
}

// Round 7
// 753.109 us; speedup vs baseline: 1.1967x; 1.0394x over previous
//
#include <hip/hip_runtime.h>
#include <hip/hip_bf16.h>

#define LTOT 4096
#define DM 256
#define BATCH 8
#define MROWS (BATCH * LTOT)     // 32768
#define NX ((size_t)MROWS * DM)  // 8388608 elements

typedef __bf16 bf16x8 __attribute__((ext_vector_type(8)));
typedef float f32x4 __attribute__((ext_vector_type(4)));

__device__ __forceinline__ float elu1(float x) {
    return x > 0.f ? x + 1.f : expf(x);
}
__device__ __forceinline__ ushort f2bf(float f) {
    unsigned u = __float_as_uint(f);
    u += 0x7FFFu + ((u >> 16) & 1u);
    return (ushort)(u >> 16);
}
__device__ __forceinline__ unsigned pkbf(float a, float b) {
    return (unsigned)f2bf(a) | ((unsigned)f2bf(b) << 16);
}
__device__ __forceinline__ float b2f(ushort u) {
    return __uint_as_float(((unsigned)u) << 16);
}

// ---------------------------------------------------------------------------
// prep: XC[b,l,c] (row stride 512, left half) = bf16(feats[b,c,l] + pos(c,l))
// ---------------------------------------------------------------------------
__global__ __launch_bounds__(256) void prep_kernel(const float* __restrict__ feats,
                                                   ushort* __restrict__ XC) {
    __shared__ float tile[32][33];
    int b = blockIdx.z;
    int l0 = blockIdx.x * 32;
    int c0 = blockIdx.y * 32;
    int tx = threadIdx.x, ty = threadIdx.y;
#pragma unroll
    for (int j = 0; j < 4; ++j) {
        int c = c0 + ty + j * 8;
        tile[ty + j * 8][tx] = feats[((size_t)(b * DM + c)) * LTOT + l0 + tx];
    }
    __syncthreads();
#pragma unroll
    for (int j = 0; j < 4; ++j) {
        int l = l0 + ty + j * 8;
        int c = c0 + tx;
        int i2 = (c >> 2) * 2;
        float dv = expf((float)i2 * -0.07195578415156063f);
        int rem = c & 3;
        int y = l >> 6, xc = l & 63;
        float pos = (rem < 2) ? (float)(xc + 1) : (float)(y + 1);
        float arg = pos * dv;
        float pe = (rem & 1) ? cosf(arg) : sinf(arg);
        float val = tile[tx][ty + j * 8] + pe;
        size_t row = (size_t)(b * LTOT + l);
        XC[row * 512 + c] = f2bf(val);
    }
}

__global__ __launch_bounds__(256) void unprep_kernel(const float* __restrict__ X,
                                                     float* __restrict__ out) {
    __shared__ float tile[32][33];
    int b = blockIdx.z;
    int l0 = blockIdx.x * 32;
    int c0 = blockIdx.y * 32;
    int tx = threadIdx.x, ty = threadIdx.y;
#pragma unroll
    for (int j = 0; j < 4; ++j) {
        int l = l0 + ty + j * 8;
        tile[ty + j * 8][tx] = X[((size_t)(b * LTOT + l)) * DM + c0 + tx];
    }
    __syncthreads();
#pragma unroll
    for (int j = 0; j < 4; ++j) {
        int c = c0 + ty + j * 8;
        out[((size_t)(b * DM + c)) * LTOT + l0 + tx] = tile[tx][ty + j * 8];
    }
}

// ---------------------------------------------------------------------------
// ALL weight transposes in one dispatch. blockIdx.x routes:
// [0,256)Wq [256,512)Wk [512,768)Wv [768,1024)Wm [1024,2048)W1 [2048,2560)W2
// ---------------------------------------------------------------------------
__global__ __launch_bounds__(256) void wtrans_all(const float* __restrict__ Wq,
                                                  const float* __restrict__ Wk,
                                                  const float* __restrict__ Wv,
                                                  const float* __restrict__ Wm,
                                                  const float* __restrict__ W1,
                                                  const float* __restrict__ W2,
                                                  ushort* __restrict__ WTqkv,
                                                  ushort* __restrict__ WTm,
                                                  ushort* __restrict__ WT1,
                                                  ushort* __restrict__ WT2) {
    __shared__ float t[32][33];
    int idx = blockIdx.x;
    const float* W;
    ushort* WT;
    int K, N, KT, z, r;
    size_t in_ls, out_ls;
    if (idx < 1024) {
        int which = idx >> 8, local = idx & 255;
        K = 256; N = 256; KT = 8; in_ls = 65536;
        if (which == 0)      { W = Wq; WT = WTqkv;          out_ls = 196608; }
        else if (which == 1) { W = Wk; WT = WTqkv + 65536;  out_ls = 196608; }
        else if (which == 2) { W = Wv; WT = WTqkv + 131072; out_ls = 196608; }
        else                 { W = Wm; WT = WTm;            out_ls = 65536; }
        z = local >> 6; r = local & 63;
    } else if (idx < 2048) {
        int local = idx - 1024;
        K = 512; N = 512; KT = 16; in_ls = 262144; out_ls = 262144;
        W = W1; WT = WT1;
        z = local >> 8; r = local & 255;
    } else {
        int local = idx - 2048;
        K = 512; N = 256; KT = 16; in_ls = 131072; out_ls = 131072;
        W = W2; WT = WT2;
        z = local >> 7; r = local & 127;
    }
    int k0 = (r % KT) * 32, n0 = (r / KT) * 32;
    const float* Wz = W + (size_t)z * in_ls;
    ushort* WTz = WT + (size_t)z * out_ls;
    int tx = threadIdx.x & 31, ty = threadIdx.x >> 5;
#pragma unroll
    for (int j = 0; j < 4; ++j)
        t[ty + j * 8][tx] = Wz[(size_t)(k0 + ty + j * 8) * N + n0 + tx];
    __syncthreads();
#pragma unroll
    for (int j = 0; j < 4; ++j)
        WTz[(size_t)(n0 + ty + j * 8) * K + k0 + tx] = f2bf(t[tx][ty + j * 8]);
}

// ---------------------------------------------------------------------------
// bf16 MFMA GEMM: Cb[M,N] = act(A[M,K] @ Bt[N,K]^T), bf16 out.
// 128x128 tile, BK=32, 4 waves 2x2, 4x4 frags of 16x16x32.
// __launch_bounds__(256,4): cap regs at 128 -> 4 blocks/CU.
// ACT: 2 relu, 3 elu+1 for col<512 else identity (QKV).
// ---------------------------------------------------------------------------
template <int ACT>
__global__ __launch_bounds__(256, 4) void gemm_bf16(const ushort* __restrict__ A, int lda,
                                                    const ushort* __restrict__ Bt,
                                                    ushort* __restrict__ Cb,
                                                    int N, int K) {
    __shared__ ushort As[4096];  // [128][32]
    __shared__ ushort Bs[4096];  // [128][32]
    int tid = threadIdx.x;
    int m0 = blockIdx.x * 128, n0 = blockIdx.y * 128;
    int wave = tid >> 6, lane = tid & 63;
    int wm = (wave >> 1) * 64, wn = (wave & 1) * 64;
    int fm = lane & 15, kg = lane >> 4;

    f32x4 acc[4][4] = {};

    for (int k0 = 0; k0 < K; k0 += 32) {
        const ushort* Ag = A + (size_t)m0 * lda + k0;
        const ushort* Bg = Bt + (size_t)n0 * K + k0;
#pragma unroll
        for (int iss = 0; iss < 2; ++iss) {
            int slot = iss * 256 + tid;
            int rr = slot >> 2, cc = (slot & 3) * 8;
            __builtin_amdgcn_global_load_lds(
                (const __attribute__((address_space(1))) void*)(Ag + (size_t)rr * lda + cc),
                (__attribute__((address_space(3))) void*)(As + iss * 2048 + wave * 512),
                16, 0, 0);
            __builtin_amdgcn_global_load_lds(
                (const __attribute__((address_space(1))) void*)(Bg + (size_t)rr * K + cc),
                (__attribute__((address_space(3))) void*)(Bs + iss * 2048 + wave * 512),
                16, 0, 0);
        }
        __syncthreads();
        bf16x8 afr[4], bfr[4];
#pragma unroll
        for (int i = 0; i < 4; ++i)
            afr[i] = *(const bf16x8*)(As + (wm + i * 16 + fm) * 32 + kg * 8);
#pragma unroll
        for (int j = 0; j < 4; ++j)
            bfr[j] = *(const bf16x8*)(Bs + (wn + j * 16 + fm) * 32 + kg * 8);
#pragma unroll
        for (int i = 0; i < 4; ++i)
#pragma unroll
            for (int j = 0; j < 4; ++j)
                acc[i][j] = __builtin_amdgcn_mfma_f32_16x16x32_bf16(afr[i], bfr[j], acc[i][j], 0, 0, 0);
        __syncthreads();
    }

#pragma unroll
    for (int i = 0; i < 4; ++i) {
        int grow0 = m0 + wm + i * 16 + kg * 4;
#pragma unroll
        for (int r = 0; r < 4; ++r) {
            size_t rowoff = (size_t)(grow0 + r) * N;
#pragma unroll
            for (int j = 0; j < 4; ++j) {
                float v = acc[i][j][r];
                int col = n0 + wn + j * 16 + fm;
                if (ACT == 2) v = fmaxf(v, 0.f);
                if (ACT == 3) v = (col < 512) ? elu1(v) : v;
                Cb[rowoff + col] = f2bf(v);
            }
        }
    }
}

// ---------------------------------------------------------------------------
// Fused GEMM + LayerNorm, retiled: 64 rows x 256 cols, 256 threads = 4 waves
// (each wave one 64-col band). Grid = 512 blocks -> 2 blocks/CU.
// RES=0 (LN1):  XC[row*512 + 256 + col] = bf16(LN(T))
// RES=1 (LN2):  x = bf16(XC left) + LN(T); XC left = bf16(x);
//               if (Xout) Xout[row][col] = x  (fp32, final layer only)
// ---------------------------------------------------------------------------
template <int RES>
__global__ __launch_bounds__(256) void gemm_ln(const ushort* __restrict__ A, int lda,
                                               const ushort* __restrict__ Bt, int K,
                                               const float* __restrict__ g,
                                               const float* __restrict__ bta,
                                               float* __restrict__ Xout,
                                               ushort* __restrict__ XC) {
    __shared__ ushort As[2048];   // [64][32]
    __shared__ ushort Bs[8192];   // [256][32]
    __shared__ float red[64 * 8];
    __shared__ float musig[64 * 2];
    int tid = threadIdx.x;
    int m0 = blockIdx.x * 64;
    int wave = tid >> 6, lane = tid & 63;
    int wc = wave;                 // column band 0..3
    int fm = lane & 15, kg = lane >> 4;

    f32x4 acc[4][4] = {};

    for (int k0 = 0; k0 < K; k0 += 32) {
        const ushort* Ag = A + (size_t)m0 * lda + k0;
        const ushort* Bg = Bt + k0;
        {
            int rr = tid >> 2, cc = (tid & 3) * 8;
            __builtin_amdgcn_global_load_lds(
                (const __attribute__((address_space(1))) void*)(Ag + (size_t)rr * lda + cc),
                (__attribute__((address_space(3))) void*)(As + wave * 512),
                16, 0, 0);
        }
#pragma unroll
        for (int iss = 0; iss < 4; ++iss) {
            int slot = iss * 256 + tid;
            int rr = slot >> 2, cc = (slot & 3) * 8;
            __builtin_amdgcn_global_load_lds(
                (const __attribute__((address_space(1))) void*)(Bg + (size_t)rr * K + cc),
                (__attribute__((address_space(3))) void*)(Bs + iss * 2048 + wave * 512),
                16, 0, 0);
        }
        __syncthreads();
        bf16x8 afr[4], bfr[4];
#pragma unroll
        for (int i = 0; i < 4; ++i)
            afr[i] = *(const bf16x8*)(As + (i * 16 + fm) * 32 + kg * 8);
#pragma unroll
        for (int j = 0; j < 4; ++j)
            bfr[j] = *(const bf16x8*)(Bs + (wc * 64 + j * 16 + fm) * 32 + kg * 8);
#pragma unroll
        for (int i = 0; i < 4; ++i)
#pragma unroll
            for (int j = 0; j < 4; ++j)
                acc[i][j] = __builtin_amdgcn_mfma_f32_16x16x32_bf16(afr[i], bfr[j], acc[i][j], 0, 0, 0);
        __syncthreads();
    }

    // per-row partial sums (this wave covers 64 of 256 cols); reduce over fm
#pragma unroll
    for (int i = 0; i < 4; ++i) {
#pragma unroll
        for (int r = 0; r < 4; ++r) {
            float s = acc[i][0][r] + acc[i][1][r] + acc[i][2][r] + acc[i][3][r];
            float q = acc[i][0][r] * acc[i][0][r] + acc[i][1][r] * acc[i][1][r] +
                      acc[i][2][r] * acc[i][2][r] + acc[i][3][r] * acc[i][3][r];
#pragma unroll
            for (int o = 1; o < 16; o <<= 1) {
                s += __shfl_xor(s, o, 64);
                q += __shfl_xor(q, o, 64);
            }
            if ((lane & 15) == 0) {
                int row = i * 16 + kg * 4 + r;
                red[row * 8 + wc] = s;
                red[row * 8 + 4 + wc] = q;
            }
        }
    }
    __syncthreads();
    if (tid < 64) {
        float s = red[tid * 8 + 0] + red[tid * 8 + 1] + red[tid * 8 + 2] + red[tid * 8 + 3];
        float q = red[tid * 8 + 4] + red[tid * 8 + 5] + red[tid * 8 + 6] + red[tid * 8 + 7];
        float mu = s * (1.f / 256.f);
        float var = q * (1.f / 256.f) - mu * mu;
        musig[tid * 2] = mu;
        musig[tid * 2 + 1] = rsqrtf(var + 1e-5f);
    }
    __syncthreads();

    float gv[4], bv[4];
#pragma unroll
    for (int j = 0; j < 4; ++j) {
        int col = wc * 64 + j * 16 + fm;
        gv[j] = g[col];
        bv[j] = bta[col];
    }
#pragma unroll
    for (int i = 0; i < 4; ++i) {
#pragma unroll
        for (int r = 0; r < 4; ++r) {
            int rl = i * 16 + kg * 4 + r;
            float mu = musig[rl * 2], rstd = musig[rl * 2 + 1];
            size_t grow = (size_t)(m0 + rl);
#pragma unroll
            for (int j = 0; j < 4; ++j) {
                int col = wc * 64 + j * 16 + fm;
                float v = (acc[i][j][r] - mu) * rstd * gv[j] + bv[j];
                if (RES) {
                    float x = b2f(XC[grow * 512 + col]) + v;
                    XC[grow * 512 + col] = f2bf(x);
                    if (Xout) Xout[grow * 256 + col] = x;
                } else {
                    XC[grow * 512 + 256 + col] = f2bf(v);
                }
            }
        }
    }
}

// ---------------------------------------------------------------------------
// KV partials, LDS-free register-blocked (round-6 proven).
// ---------------------------------------------------------------------------
__global__ __launch_bounds__(256) void kv_kernel(const ushort* __restrict__ Kf,
                                                 const ushort* __restrict__ Vf,
                                                 int str,
                                                 float* __restrict__ KVp,
                                                 float* __restrict__ KSp) {
    __shared__ float redv[3][8][8][16];  // 12 KB
    __shared__ float redk[3][8][4];
    int tid = threadIdx.x;
    int bh = blockIdx.x, sp = blockIdx.y;
    int b = bh >> 3, h = bh & 7;
    int sg = tid >> 6, d2 = (tid >> 3) & 7, v2 = tid & 7;
    size_t rbase = (size_t)(b * LTOT + sp * 512 + sg * 128) * str;
    const ushort* Kp = Kf + rbase + h * 32 + d2 * 4;
    const ushort* Vp = Vf + rbase + h * 32 + v2 * 4;
    float acc[4][4] = {};
    float ks[4] = {};
#pragma unroll 4
    for (int s = 0; s < 128; ++s) {
        ushort4 k4 = *(const ushort4*)(Kp + (size_t)s * str);
        ushort4 v4 = *(const ushort4*)(Vp + (size_t)s * str);
        float kk0 = b2f(k4.x), kk1 = b2f(k4.y), kk2 = b2f(k4.z), kk3 = b2f(k4.w);
        float vv0 = b2f(v4.x), vv1 = b2f(v4.y), vv2 = b2f(v4.z), vv3 = b2f(v4.w);
        acc[0][0] += kk0 * vv0; acc[0][1] += kk0 * vv1; acc[0][2] += kk0 * vv2; acc[0][3] += kk0 * vv3;
        acc[1][0] += kk1 * vv0; acc[1][1] += kk1 * vv1; acc[1][2] += kk1 * vv2; acc[1][3] += kk1 * vv3;
        acc[2][0] += kk2 * vv0; acc[2][1] += kk2 * vv1; acc[2][2] += kk2 * vv2; acc[2][3] += kk2 * vv3;
        acc[3][0] += kk3 * vv0; acc[3][1] += kk3 * vv1; acc[3][2] += kk3 * vv2; acc[3][3] += kk3 * vv3;
        ks[0] += kk0; ks[1] += kk1; ks[2] += kk2; ks[3] += kk3;
    }
    if (sg > 0) {
#pragma unroll
        for (int i = 0; i < 4; ++i)
#pragma unroll
            for (int j = 0; j < 4; ++j)
                redv[sg - 1][d2][v2][i * 4 + j] = acc[i][j];
        if (v2 == 0) {
#pragma unroll
            for (int i = 0; i < 4; ++i) redk[sg - 1][d2][i] = ks[i];
        }
    }
    __syncthreads();
    if (sg == 0) {
#pragma unroll
        for (int t = 0; t < 3; ++t)
#pragma unroll
            for (int i = 0; i < 4; ++i)
#pragma unroll
                for (int j = 0; j < 4; ++j)
                    acc[i][j] += redv[t][d2][v2][i * 4 + j];
        float* base = KVp + (size_t)(sp * 64 + bh) * 1024;
#pragma unroll
        for (int i = 0; i < 4; ++i) {
            float4 o = make_float4(acc[i][0], acc[i][1], acc[i][2], acc[i][3]);
            *(float4*)(base + (d2 * 4 + i) * 32 + v2 * 4) = o;
        }
        if (v2 == 0) {
#pragma unroll
            for (int t = 0; t < 3; ++t)
#pragma unroll
                for (int i = 0; i < 4; ++i) ks[i] += redk[t][d2][i];
#pragma unroll
            for (int i = 0; i < 4; ++i)
                KSp[(sp * 64 + bh) * 32 + d2 * 4 + i] = ks[i];
        }
    }
}

// ---------------------------------------------------------------------------
// reduce partials: KV[bh] = sum_sp KVp[sp][bh]; KS likewise (one dispatch)
// ---------------------------------------------------------------------------
__global__ __launch_bounds__(256) void kvreduce_kernel(const float* __restrict__ KVp,
                                                       const float* __restrict__ KSp,
                                                       float* __restrict__ KV,
                                                       float* __restrict__ KS) {
    int bh = blockIdx.x;
    int t = threadIdx.x;
    float4 s = make_float4(0.f, 0.f, 0.f, 0.f);
#pragma unroll
    for (int sp = 0; sp < 8; ++sp) {
        float4 v = *(const float4*)(KVp + ((size_t)(sp * 64 + bh)) * 1024 + t * 4);
        s.x += v.x; s.y += v.y; s.z += v.z; s.w += v.w;
    }
    *(float4*)(KV + (size_t)bh * 1024 + t * 4) = s;
    if (t < 32) {
        float ks = 0.f;
#pragma unroll
        for (int sp = 0; sp < 8; ++sp) ks += KSp[(sp * 64 + bh) * 32 + t];
        KS[bh * 32 + t] = ks;
    }
}

// ---------------------------------------------------------------------------
// msg[b,l,h,v] = (sum_d Q*KV) / (sum_d Q*KS + eps); Q bf16 stride qstr.
// ---------------------------------------------------------------------------
__global__ __launch_bounds__(256) void msg_kernel(const ushort* __restrict__ Qb, int qstr,
                                                  const float* __restrict__ KV,
                                                  const float* __restrict__ KS,
                                                  ushort* __restrict__ Msgb) {
    __shared__ float KVs[8 * 1032];
    __shared__ float KSs[256];
    int tid = threadIdx.x;
    int b = blockIdx.y;
    int l0 = blockIdx.x * 32;
    for (int i = tid; i < 8192; i += 256) {
        int h = i >> 10, r = i & 1023;
        KVs[h * 1032 + r] = KV[((size_t)(b * 8 + h)) * 1024 + r];
    }
    KSs[tid] = KS[b * 256 + tid];
    __syncthreads();
    int l = l0 + (tid >> 3);
    int h = tid & 7;
    const ushort* qp = Qb + ((size_t)(b * LTOT + l)) * qstr + h * 32;
    float qv[32];
#pragma unroll
    for (int i = 0; i < 8; ++i) {
        ushort4 q4 = *(const ushort4*)(qp + i * 4);
        qv[i * 4 + 0] = b2f(q4.x); qv[i * 4 + 1] = b2f(q4.y);
        qv[i * 4 + 2] = b2f(q4.z); qv[i * 4 + 3] = b2f(q4.w);
    }
    float den = 1e-6f;
#pragma unroll
    for (int d2 = 0; d2 < 32; ++d2) den += qv[d2] * KSs[h * 32 + d2];
    float rz = 1.f / den;
    float acc[32] = {};
#pragma unroll
    for (int d2 = 0; d2 < 32; ++d2) {
        float qd = qv[d2];
        const float* kvp = &KVs[h * 1032 + d2 * 32];
#pragma unroll
        for (int v = 0; v < 32; ++v) acc[v] += qd * kvp[v];
    }
    ushort* op = Msgb + ((size_t)(b * LTOT + l)) * DM + h * 32;
#pragma unroll
    for (int i = 0; i < 4; ++i) {
        uint2 p;
        p.x = pkbf(acc[i * 8 + 0] * rz, acc[i * 8 + 1] * rz);
        p.y = pkbf(acc[i * 8 + 2] * rz, acc[i * 8 + 3] * rz);
        uint2 p2;
        p2.x = pkbf(acc[i * 8 + 4] * rz, acc[i * 8 + 5] * rz);
        p2.y = pkbf(acc[i * 8 + 6] * rz, acc[i * 8 + 7] * rz);
        *(uint2*)(op + i * 8) = p;
        *(uint2*)(op + i * 8 + 4) = p2;
    }
}

// ---------------------------------------------------------------------------
// Orchestration
// ---------------------------------------------------------------------------
extern "C" void kernel_launch(void* const* d_in, const int* in_sizes, int n_in,
                              void* d_out, int out_size, void* d_ws, size_t ws_size,
                              hipStream_t stream) {
    const float* feats = (const float*)d_in[0];
    const float* Wq = (const float*)d_in[1];
    const float* Wk = (const float*)d_in[2];
    const float* Wv = (const float*)d_in[3];
    const float* Wm = (const float*)d_in[4];
    const float* W1 = (const float*)d_in[5];
    const float* W2 = (const float*)d_in[6];
    const float* g1 = (const float*)d_in[7];
    const float* b1 = (const float*)d_in[8];
    const float* g2 = (const float*)d_in[9];
    const float* b2 = (const float*)d_in[10];

    float* ws = (float*)d_ws;
    float* X = ws;                            // fp32 final x (written layer 3 only)
    ushort* XC = (ushort*)(ws + NX);          // bf16 [32768][512]: [x | LN1(msg)]
    ushort* QKVb = (ushort*)(ws + 2 * NX);    // bf16 [32768][768]; aliased by HBb
    ushort* HBb = QKVb;                       // bf16 [32768][512] MLP hidden

    // d_out doubles as scratch until the final unprep (32 MB)
    float* dout = (float*)d_out;
    ushort* msgb = (ushort*)dout;             // bf16 [32768][256] (16 MB)
    ushort* WB = (ushort*)dout + NX;
    ushort* WTqkv = WB;                       // [4][768][256]
    ushort* WTm = WB + 4 * 196608;            // [4][256][256]
    ushort* WT1 = WTm + 4 * 65536;            // [4][512][512]
    ushort* WT2 = WT1 + 4 * 262144;           // [4][256][512]
    float* KVp = dout + (NX + 2621440) / 2;   // [8][64][1024]
    float* KSp = KVp + 524288;                // [8][64][32]
    float* KV = KSp + 16384;                  // [64][1024]
    float* KS = KV + 65536;                   // [64][32]

    wtrans_all<<<2560, 256, 0, stream>>>(Wq, Wk, Wv, Wm, W1, W2, WTqkv, WTm, WT1, WT2);
    prep_kernel<<<dim3(128, 8, 8), dim3(32, 8), 0, stream>>>(feats, XC);

    for (int layer = 0; layer < 4; ++layer) {
        const ushort* wtqkv = WTqkv + (size_t)layer * 196608;
        const ushort* wtm = WTm + (size_t)layer * 65536;
        const ushort* wt1 = WT1 + (size_t)layer * 262144;
        const ushort* wt2 = WT2 + (size_t)layer * 131072;
        const float* lg1 = g1 + layer * DM;
        const float* lb1 = b1 + layer * DM;
        const float* lg2 = g2 + layer * DM;
        const float* lb2 = b2 + layer * DM;

        // QKV fused: [32768][768] = elu1/elu1/id( XC[:, :256] @ [Wq|Wk|Wv] )
        gemm_bf16<3><<<dim3(256, 6), 256, 0, stream>>>(XC, 512, wtqkv, QKVb, 768, 256);
        kv_kernel<<<dim3(64, 8), 256, 0, stream>>>(QKVb + 256, QKVb + 512, 768, KVp, KSp);
        kvreduce_kernel<<<64, 256, 0, stream>>>(KVp, KSp, KV, KS);
        msg_kernel<<<dim3(128, 8), 256, 0, stream>>>(QKVb, 768, KV, KS, msgb);
        // Wm GEMM + LN1 fused -> XC right half
        gemm_ln<0><<<512, 256, 0, stream>>>(msgb, 256, wtm, 256, lg1, lb1, nullptr, XC);
        // MLP1: relu( XC[:, :512] @ W1 ) -> HBb  (aliases QKVb, which is dead)
        gemm_bf16<2><<<dim3(256, 4), 256, 0, stream>>>(XC, 512, wt1, HBb, 512, 512);
        // MLP2 + LN2 + bf16 residual -> XC left; final layer also writes fp32 X
        gemm_ln<1><<<512, 256, 0, stream>>>(HBb, 512, wt2, 512, lg2, lb2,
                                            (layer == 3) ? X : nullptr, XC);
    }

    unprep_kernel<<<dim3(128, 8, 8), dim3(32, 8), 0, stream>>>(X, dout);
}

// Round 8
// 649.167 us; speedup vs baseline: 1.3883x; 1.1601x over previous
//
#include <hip/hip_runtime.h>
#include <hip/hip_bf16.h>

#define LTOT 4096
#define DM 256
#define BATCH 8
#define MROWS (BATCH * LTOT)     // 32768
#define NX ((size_t)MROWS * DM)  // 8388608 elements

typedef __bf16 bf16x8 __attribute__((ext_vector_type(8)));
typedef float f32x4 __attribute__((ext_vector_type(4)));

__device__ __forceinline__ float elu1(float x) {
    return x > 0.f ? x + 1.f : expf(x);
}
__device__ __forceinline__ ushort f2bf(float f) {
    unsigned u = __float_as_uint(f);
    u += 0x7FFFu + ((u >> 16) & 1u);
    return (ushort)(u >> 16);
}
__device__ __forceinline__ unsigned pkbf(float a, float b) {
    return (unsigned)f2bf(a) | ((unsigned)f2bf(b) << 16);
}
__device__ __forceinline__ float b2f(ushort u) {
    return __uint_as_float(((unsigned)u) << 16);
}

// ---------------------------------------------------------------------------
// prep: XC[b,l,c] (row stride 512, left half) = bf16(feats[b,c,l] + pos(c,l))
// ---------------------------------------------------------------------------
__global__ __launch_bounds__(256) void prep_kernel(const float* __restrict__ feats,
                                                   ushort* __restrict__ XC) {
    __shared__ float tile[32][33];
    int b = blockIdx.z;
    int l0 = blockIdx.x * 32;
    int c0 = blockIdx.y * 32;
    int tx = threadIdx.x, ty = threadIdx.y;
#pragma unroll
    for (int j = 0; j < 4; ++j) {
        int c = c0 + ty + j * 8;
        tile[ty + j * 8][tx] = feats[((size_t)(b * DM + c)) * LTOT + l0 + tx];
    }
    __syncthreads();
#pragma unroll
    for (int j = 0; j < 4; ++j) {
        int l = l0 + ty + j * 8;
        int c = c0 + tx;
        int i2 = (c >> 2) * 2;
        float dv = expf((float)i2 * -0.07195578415156063f);
        int rem = c & 3;
        int y = l >> 6, xc = l & 63;
        float pos = (rem < 2) ? (float)(xc + 1) : (float)(y + 1);
        float arg = pos * dv;
        float pe = (rem & 1) ? cosf(arg) : sinf(arg);
        float val = tile[tx][ty + j * 8] + pe;
        size_t row = (size_t)(b * LTOT + l);
        XC[row * 512 + c] = f2bf(val);
    }
}

__global__ __launch_bounds__(256) void unprep_kernel(const float* __restrict__ X,
                                                     float* __restrict__ out) {
    __shared__ float tile[32][33];
    int b = blockIdx.z;
    int l0 = blockIdx.x * 32;
    int c0 = blockIdx.y * 32;
    int tx = threadIdx.x, ty = threadIdx.y;
#pragma unroll
    for (int j = 0; j < 4; ++j) {
        int l = l0 + ty + j * 8;
        tile[ty + j * 8][tx] = X[((size_t)(b * LTOT + l)) * DM + c0 + tx];
    }
    __syncthreads();
#pragma unroll
    for (int j = 0; j < 4; ++j) {
        int c = c0 + ty + j * 8;
        out[((size_t)(b * DM + c)) * LTOT + l0 + tx] = tile[tx][ty + j * 8];
    }
}

// ---------------------------------------------------------------------------
// ALL weight transposes in one dispatch. blockIdx.x routes:
// [0,256)Wq [256,512)Wk [512,768)Wv [768,1024)Wm [1024,2048)W1 [2048,2560)W2
// ---------------------------------------------------------------------------
__global__ __launch_bounds__(256) void wtrans_all(const float* __restrict__ Wq,
                                                  const float* __restrict__ Wk,
                                                  const float* __restrict__ Wv,
                                                  const float* __restrict__ Wm,
                                                  const float* __restrict__ W1,
                                                  const float* __restrict__ W2,
                                                  ushort* __restrict__ WTqkv,
                                                  ushort* __restrict__ WTm,
                                                  ushort* __restrict__ WT1,
                                                  ushort* __restrict__ WT2) {
    __shared__ float t[32][33];
    int idx = blockIdx.x;
    const float* W;
    ushort* WT;
    int K, N, KT, z, r;
    size_t in_ls, out_ls;
    if (idx < 1024) {
        int which = idx >> 8, local = idx & 255;
        K = 256; N = 256; KT = 8; in_ls = 65536;
        if (which == 0)      { W = Wq; WT = WTqkv;          out_ls = 196608; }
        else if (which == 1) { W = Wk; WT = WTqkv + 65536;  out_ls = 196608; }
        else if (which == 2) { W = Wv; WT = WTqkv + 131072; out_ls = 196608; }
        else                 { W = Wm; WT = WTm;            out_ls = 65536; }
        z = local >> 6; r = local & 63;
    } else if (idx < 2048) {
        int local = idx - 1024;
        K = 512; N = 512; KT = 16; in_ls = 262144; out_ls = 262144;
        W = W1; WT = WT1;
        z = local >> 8; r = local & 255;
    } else {
        int local = idx - 2048;
        K = 512; N = 256; KT = 16; in_ls = 131072; out_ls = 131072;
        W = W2; WT = WT2;
        z = local >> 7; r = local & 127;
    }
    int k0 = (r % KT) * 32, n0 = (r / KT) * 32;
    const float* Wz = W + (size_t)z * in_ls;
    ushort* WTz = WT + (size_t)z * out_ls;
    int tx = threadIdx.x & 31, ty = threadIdx.x >> 5;
#pragma unroll
    for (int j = 0; j < 4; ++j)
        t[ty + j * 8][tx] = Wz[(size_t)(k0 + ty + j * 8) * N + n0 + tx];
    __syncthreads();
#pragma unroll
    for (int j = 0; j < 4; ++j)
        WTz[(size_t)(n0 + ty + j * 8) * K + k0 + tx] = f2bf(t[tx][ty + j * 8]);
}

// ---------------------------------------------------------------------------
// bf16 MFMA GEMM: Cb[M,N] = act(A[M,K] @ Bt[N,K]^T), bf16 out.
// 128x128 tile, BK=32, 4 waves 2x2, 4x4 frags of 16x16x32.
// __launch_bounds__(256,4): cap regs at 128 -> 4 blocks/CU.
// ACT: 2 relu, 3 elu+1 for col<512 else identity (QKV).
// ---------------------------------------------------------------------------
template <int ACT>
__global__ __launch_bounds__(256, 4) void gemm_bf16(const ushort* __restrict__ A, int lda,
                                                    const ushort* __restrict__ Bt,
                                                    ushort* __restrict__ Cb,
                                                    int N, int K) {
    __shared__ ushort As[4096];  // [128][32]
    __shared__ ushort Bs[4096];  // [128][32]
    int tid = threadIdx.x;
    int m0 = blockIdx.x * 128, n0 = blockIdx.y * 128;
    int wave = tid >> 6, lane = tid & 63;
    int wm = (wave >> 1) * 64, wn = (wave & 1) * 64;
    int fm = lane & 15, kg = lane >> 4;

    f32x4 acc[4][4] = {};

    for (int k0 = 0; k0 < K; k0 += 32) {
        const ushort* Ag = A + (size_t)m0 * lda + k0;
        const ushort* Bg = Bt + (size_t)n0 * K + k0;
#pragma unroll
        for (int iss = 0; iss < 2; ++iss) {
            int slot = iss * 256 + tid;
            int rr = slot >> 2, cc = (slot & 3) * 8;
            __builtin_amdgcn_global_load_lds(
                (const __attribute__((address_space(1))) void*)(Ag + (size_t)rr * lda + cc),
                (__attribute__((address_space(3))) void*)(As + iss * 2048 + wave * 512),
                16, 0, 0);
            __builtin_amdgcn_global_load_lds(
                (const __attribute__((address_space(1))) void*)(Bg + (size_t)rr * K + cc),
                (__attribute__((address_space(3))) void*)(Bs + iss * 2048 + wave * 512),
                16, 0, 0);
        }
        __syncthreads();
        bf16x8 afr[4], bfr[4];
#pragma unroll
        for (int i = 0; i < 4; ++i)
            afr[i] = *(const bf16x8*)(As + (wm + i * 16 + fm) * 32 + kg * 8);
#pragma unroll
        for (int j = 0; j < 4; ++j)
            bfr[j] = *(const bf16x8*)(Bs + (wn + j * 16 + fm) * 32 + kg * 8);
#pragma unroll
        for (int i = 0; i < 4; ++i)
#pragma unroll
            for (int j = 0; j < 4; ++j)
                acc[i][j] = __builtin_amdgcn_mfma_f32_16x16x32_bf16(afr[i], bfr[j], acc[i][j], 0, 0, 0);
        __syncthreads();
    }

#pragma unroll
    for (int i = 0; i < 4; ++i) {
        int grow0 = m0 + wm + i * 16 + kg * 4;
#pragma unroll
        for (int r = 0; r < 4; ++r) {
            size_t rowoff = (size_t)(grow0 + r) * N;
#pragma unroll
            for (int j = 0; j < 4; ++j) {
                float v = acc[i][j][r];
                int col = n0 + wn + j * 16 + fm;
                if (ACT == 2) v = fmaxf(v, 0.f);
                if (ACT == 3) v = (col < 512) ? elu1(v) : v;
                Cb[rowoff + col] = f2bf(v);
            }
        }
    }
}

// ---------------------------------------------------------------------------
// Fused GEMM + LayerNorm: 64 rows x 256 cols, 256 threads = 4 waves.
// RES=0 (LN1):  XC[row*512 + 256 + col] = bf16(LN(T))
// RES=1 (LN2):  x = bf16(XC left) + LN(T); XC left = bf16(x);
//               if (Xout) Xout[row][col] = x  (fp32, final layer only)
// ---------------------------------------------------------------------------
template <int RES>
__global__ __launch_bounds__(256) void gemm_ln(const ushort* __restrict__ A, int lda,
                                               const ushort* __restrict__ Bt, int K,
                                               const float* __restrict__ g,
                                               const float* __restrict__ bta,
                                               float* __restrict__ Xout,
                                               ushort* __restrict__ XC) {
    __shared__ ushort As[2048];   // [64][32]
    __shared__ ushort Bs[8192];   // [256][32]
    __shared__ float red[64 * 8];
    __shared__ float musig[64 * 2];
    int tid = threadIdx.x;
    int m0 = blockIdx.x * 64;
    int wave = tid >> 6, lane = tid & 63;
    int wc = wave;                 // column band 0..3
    int fm = lane & 15, kg = lane >> 4;

    f32x4 acc[4][4] = {};

    for (int k0 = 0; k0 < K; k0 += 32) {
        const ushort* Ag = A + (size_t)m0 * lda + k0;
        const ushort* Bg = Bt + k0;
        {
            int rr = tid >> 2, cc = (tid & 3) * 8;
            __builtin_amdgcn_global_load_lds(
                (const __attribute__((address_space(1))) void*)(Ag + (size_t)rr * lda + cc),
                (__attribute__((address_space(3))) void*)(As + wave * 512),
                16, 0, 0);
        }
#pragma unroll
        for (int iss = 0; iss < 4; ++iss) {
            int slot = iss * 256 + tid;
            int rr = slot >> 2, cc = (slot & 3) * 8;
            __builtin_amdgcn_global_load_lds(
                (const __attribute__((address_space(1))) void*)(Bg + (size_t)rr * K + cc),
                (__attribute__((address_space(3))) void*)(Bs + iss * 2048 + wave * 512),
                16, 0, 0);
        }
        __syncthreads();
        bf16x8 afr[4], bfr[4];
#pragma unroll
        for (int i = 0; i < 4; ++i)
            afr[i] = *(const bf16x8*)(As + (i * 16 + fm) * 32 + kg * 8);
#pragma unroll
        for (int j = 0; j < 4; ++j)
            bfr[j] = *(const bf16x8*)(Bs + (wc * 64 + j * 16 + fm) * 32 + kg * 8);
#pragma unroll
        for (int i = 0; i < 4; ++i)
#pragma unroll
            for (int j = 0; j < 4; ++j)
                acc[i][j] = __builtin_amdgcn_mfma_f32_16x16x32_bf16(afr[i], bfr[j], acc[i][j], 0, 0, 0);
        __syncthreads();
    }

#pragma unroll
    for (int i = 0; i < 4; ++i) {
#pragma unroll
        for (int r = 0; r < 4; ++r) {
            float s = acc[i][0][r] + acc[i][1][r] + acc[i][2][r] + acc[i][3][r];
            float q = acc[i][0][r] * acc[i][0][r] + acc[i][1][r] * acc[i][1][r] +
                      acc[i][2][r] * acc[i][2][r] + acc[i][3][r] * acc[i][3][r];
#pragma unroll
            for (int o = 1; o < 16; o <<= 1) {
                s += __shfl_xor(s, o, 64);
                q += __shfl_xor(q, o, 64);
            }
            if ((lane & 15) == 0) {
                int row = i * 16 + kg * 4 + r;
                red[row * 8 + wc] = s;
                red[row * 8 + 4 + wc] = q;
            }
        }
    }
    __syncthreads();
    if (tid < 64) {
        float s = red[tid * 8 + 0] + red[tid * 8 + 1] + red[tid * 8 + 2] + red[tid * 8 + 3];
        float q = red[tid * 8 + 4] + red[tid * 8 + 5] + red[tid * 8 + 6] + red[tid * 8 + 7];
        float mu = s * (1.f / 256.f);
        float var = q * (1.f / 256.f) - mu * mu;
        musig[tid * 2] = mu;
        musig[tid * 2 + 1] = rsqrtf(var + 1e-5f);
    }
    __syncthreads();

    float gv[4], bv[4];
#pragma unroll
    for (int j = 0; j < 4; ++j) {
        int col = wc * 64 + j * 16 + fm;
        gv[j] = g[col];
        bv[j] = bta[col];
    }
#pragma unroll
    for (int i = 0; i < 4; ++i) {
#pragma unroll
        for (int r = 0; r < 4; ++r) {
            int rl = i * 16 + kg * 4 + r;
            float mu = musig[rl * 2], rstd = musig[rl * 2 + 1];
            size_t grow = (size_t)(m0 + rl);
#pragma unroll
            for (int j = 0; j < 4; ++j) {
                int col = wc * 64 + j * 16 + fm;
                float v = (acc[i][j][r] - mu) * rstd * gv[j] + bv[j];
                if (RES) {
                    float x = b2f(XC[grow * 512 + col]) + v;
                    XC[grow * 512 + col] = f2bf(x);
                    if (Xout) Xout[grow * 256 + col] = x;
                } else {
                    XC[grow * 512 + 256 + col] = f2bf(v);
                }
            }
        }
    }
}

// ---------------------------------------------------------------------------
// KV partials, LDS-free register-blocked (proven).
// ---------------------------------------------------------------------------
__global__ __launch_bounds__(256) void kv_kernel(const ushort* __restrict__ Kf,
                                                 const ushort* __restrict__ Vf,
                                                 int str,
                                                 float* __restrict__ KVp,
                                                 float* __restrict__ KSp) {
    __shared__ float redv[3][8][8][16];  // 12 KB
    __shared__ float redk[3][8][4];
    int tid = threadIdx.x;
    int bh = blockIdx.x, sp = blockIdx.y;
    int b = bh >> 3, h = bh & 7;
    int sg = tid >> 6, d2 = (tid >> 3) & 7, v2 = tid & 7;
    size_t rbase = (size_t)(b * LTOT + sp * 512 + sg * 128) * str;
    const ushort* Kp = Kf + rbase + h * 32 + d2 * 4;
    const ushort* Vp = Vf + rbase + h * 32 + v2 * 4;
    float acc[4][4] = {};
    float ks[4] = {};
#pragma unroll 4
    for (int s = 0; s < 128; ++s) {
        ushort4 k4 = *(const ushort4*)(Kp + (size_t)s * str);
        ushort4 v4 = *(const ushort4*)(Vp + (size_t)s * str);
        float kk0 = b2f(k4.x), kk1 = b2f(k4.y), kk2 = b2f(k4.z), kk3 = b2f(k4.w);
        float vv0 = b2f(v4.x), vv1 = b2f(v4.y), vv2 = b2f(v4.z), vv3 = b2f(v4.w);
        acc[0][0] += kk0 * vv0; acc[0][1] += kk0 * vv1; acc[0][2] += kk0 * vv2; acc[0][3] += kk0 * vv3;
        acc[1][0] += kk1 * vv0; acc[1][1] += kk1 * vv1; acc[1][2] += kk1 * vv2; acc[1][3] += kk1 * vv3;
        acc[2][0] += kk2 * vv0; acc[2][1] += kk2 * vv1; acc[2][2] += kk2 * vv2; acc[2][3] += kk2 * vv3;
        acc[3][0] += kk3 * vv0; acc[3][1] += kk3 * vv1; acc[3][2] += kk3 * vv2; acc[3][3] += kk3 * vv3;
        ks[0] += kk0; ks[1] += kk1; ks[2] += kk2; ks[3] += kk3;
    }
    if (sg > 0) {
#pragma unroll
        for (int i = 0; i < 4; ++i)
#pragma unroll
            for (int j = 0; j < 4; ++j)
                redv[sg - 1][d2][v2][i * 4 + j] = acc[i][j];
        if (v2 == 0) {
#pragma unroll
            for (int i = 0; i < 4; ++i) redk[sg - 1][d2][i] = ks[i];
        }
    }
    __syncthreads();
    if (sg == 0) {
#pragma unroll
        for (int t = 0; t < 3; ++t)
#pragma unroll
            for (int i = 0; i < 4; ++i)
#pragma unroll
                for (int j = 0; j < 4; ++j)
                    acc[i][j] += redv[t][d2][v2][i * 4 + j];
        float* base = KVp + (size_t)(sp * 64 + bh) * 1024;
#pragma unroll
        for (int i = 0; i < 4; ++i) {
            float4 o = make_float4(acc[i][0], acc[i][1], acc[i][2], acc[i][3]);
            *(float4*)(base + (d2 * 4 + i) * 32 + v2 * 4) = o;
        }
        if (v2 == 0) {
#pragma unroll
            for (int t = 0; t < 3; ++t)
#pragma unroll
                for (int i = 0; i < 4; ++i) ks[i] += redk[t][d2][i];
#pragma unroll
            for (int i = 0; i < 4; ++i)
                KSp[(sp * 64 + bh) * 32 + d2 * 4 + i] = ks[i];
        }
    }
}

// ---------------------------------------------------------------------------
// reduce partials -> KVT bf16 [bh][v][d] (transposed, mfma-B layout) + KS fp32
// ---------------------------------------------------------------------------
__global__ __launch_bounds__(256) void kvreduce_kernel(const float* __restrict__ KVp,
                                                       const float* __restrict__ KSp,
                                                       ushort* __restrict__ KVT,
                                                       float* __restrict__ KS) {
    int bh = blockIdx.x;
    int t = threadIdx.x;
    float4 s = make_float4(0.f, 0.f, 0.f, 0.f);
#pragma unroll
    for (int sp = 0; sp < 8; ++sp) {
        float4 v = *(const float4*)(KVp + ((size_t)(sp * 64 + bh)) * 1024 + t * 4);
        s.x += v.x; s.y += v.y; s.z += v.z; s.w += v.w;
    }
    // KVp element (d, v): d = t>>3, v0 = (t&7)*4 -> write KVT[bh][v][d]
    int d = t >> 3, v0 = (t & 7) * 4;
    ushort* dst = KVT + (size_t)bh * 1024 + d;
    dst[(v0 + 0) * 32] = f2bf(s.x);
    dst[(v0 + 1) * 32] = f2bf(s.y);
    dst[(v0 + 2) * 32] = f2bf(s.z);
    dst[(v0 + 3) * 32] = f2bf(s.w);
    if (t < 32) {
        float ks = 0.f;
#pragma unroll
        for (int sp = 0; sp < 8; ++sp) ks += KSp[(sp * 64 + bh) * 32 + t];
        KS[bh * 32 + t] = ks;
    }
}

// ---------------------------------------------------------------------------
// msg via MFMA: msg[l, h*32+v] = (Q[l,h]·KV[h])[v] / (Q[l,h]·KS[h] + eps)
// Block: 64 rows of one b, 256 threads = 4 waves (16 rows each), all 8 heads.
// KVT staged in LDS with 80B v-stride (2-way banks = free). Q loaded direct
// from global (bf16x8/lane A-frags). Denominator in fp32 VALU + shfl reduce.
// ---------------------------------------------------------------------------
__global__ __launch_bounds__(256) void msg_mfma(const ushort* __restrict__ Qb, int qstr,
                                                const ushort* __restrict__ KVT,
                                                const float* __restrict__ KS,
                                                ushort* __restrict__ Msgb) {
    __shared__ ushort kvs[8 * 1280];  // [h][v][40] ushorts, 20 KB
    int tid = threadIdx.x;
    int b = blockIdx.y;
    int lc = blockIdx.x;  // 64-row chunk
    // stage KVT for this b: 8*32*32 = 8192 ushorts
    {
        const ushort* src = KVT + (size_t)b * 8192;
#pragma unroll
        for (int it = 0; it < 4; ++it) {
            int base = it * 2048 + tid * 8;
            int h = base >> 10, rem = base & 1023;
            int v = rem >> 5, d = rem & 31;
            bf16x8 val = *(const bf16x8*)(src + base);
            *(bf16x8*)(kvs + h * 1280 + v * 40 + d) = val;
        }
    }
    __syncthreads();
    int wave = tid >> 6, lane = tid & 63;
    int fm = lane & 15, kg = lane >> 4;
    int row0 = b * LTOT + lc * 64 + wave * 16;

    for (int h = 0; h < 8; ++h) {
        // A-frag: Q[row0+fm][h*32 + kg*8 ..+8]
        bf16x8 afr = *(const bf16x8*)(Qb + (size_t)(row0 + fm) * qstr + h * 32 + kg * 8);
        // B-frags from LDS
        bf16x8 bfr0 = *(const bf16x8*)(kvs + h * 1280 + fm * 40 + kg * 8);
        bf16x8 bfr1 = *(const bf16x8*)(kvs + h * 1280 + (16 + fm) * 40 + kg * 8);
        f32x4 acc0 = {}, acc1 = {};
        acc0 = __builtin_amdgcn_mfma_f32_16x16x32_bf16(afr, bfr0, acc0, 0, 0, 0);
        acc1 = __builtin_amdgcn_mfma_f32_16x16x32_bf16(afr, bfr1, acc1, 0, 0, 0);
        // denominator: den[fm] = sum_k Q[fm,k]*KS[k]  (fp32)
        const float* ksp = KS + (b * 8 + h) * 32 + kg * 8;
        float4 ka = *(const float4*)ksp;
        float4 kb = *(const float4*)(ksp + 4);
        float den = (float)afr[0] * ka.x + (float)afr[1] * ka.y +
                    (float)afr[2] * ka.z + (float)afr[3] * ka.w +
                    (float)afr[4] * kb.x + (float)afr[5] * kb.y +
                    (float)afr[6] * kb.z + (float)afr[7] * kb.w;
        den += __shfl_xor(den, 16, 64);
        den += __shfl_xor(den, 32, 64);
        float rz = 1.f / (den + 1e-6f);
        // store: D row = kg*4+r (within 16-tile), col = fm / 16+fm
#pragma unroll
        for (int r = 0; r < 4; ++r) {
            int rr = kg * 4 + r;
            float rzr = __shfl(rz, (kg << 4) | rr, 64);
            size_t ro = (size_t)(row0 + rr) * DM + h * 32;
            Msgb[ro + fm] = f2bf(acc0[r] * rzr);
            Msgb[ro + 16 + fm] = f2bf(acc1[r] * rzr);
        }
    }
}

// ---------------------------------------------------------------------------
// Orchestration
// ---------------------------------------------------------------------------
extern "C" void kernel_launch(void* const* d_in, const int* in_sizes, int n_in,
                              void* d_out, int out_size, void* d_ws, size_t ws_size,
                              hipStream_t stream) {
    const float* feats = (const float*)d_in[0];
    const float* Wq = (const float*)d_in[1];
    const float* Wk = (const float*)d_in[2];
    const float* Wv = (const float*)d_in[3];
    const float* Wm = (const float*)d_in[4];
    const float* W1 = (const float*)d_in[5];
    const float* W2 = (const float*)d_in[6];
    const float* g1 = (const float*)d_in[7];
    const float* b1 = (const float*)d_in[8];
    const float* g2 = (const float*)d_in[9];
    const float* b2 = (const float*)d_in[10];

    float* ws = (float*)d_ws;
    float* X = ws;                            // fp32 final x (written layer 3 only)
    ushort* XC = (ushort*)(ws + NX);          // bf16 [32768][512]: [x | LN1(msg)]
    ushort* QKVb = (ushort*)(ws + 2 * NX);    // bf16 [32768][768]; aliased by HBb
    ushort* HBb = QKVb;                       // bf16 [32768][512] MLP hidden

    // d_out doubles as scratch until the final unprep (32 MB)
    float* dout = (float*)d_out;
    ushort* msgb = (ushort*)dout;             // bf16 [32768][256] (16 MB)
    ushort* WB = (ushort*)dout + NX;
    ushort* WTqkv = WB;                       // [4][768][256]
    ushort* WTm = WB + 4 * 196608;            // [4][256][256]
    ushort* WT1 = WTm + 4 * 65536;            // [4][512][512]
    ushort* WT2 = WT1 + 4 * 262144;           // [4][256][512]
    float* KVp = dout + (NX + 2621440) / 2;   // [8][64][1024]
    float* KSp = KVp + 524288;                // [8][64][32]
    ushort* KVT = (ushort*)(KSp + 16384);     // [64][32][32] bf16 transposed
    float* KS = (float*)(KVT + 65536);        // [64][32]

    wtrans_all<<<2560, 256, 0, stream>>>(Wq, Wk, Wv, Wm, W1, W2, WTqkv, WTm, WT1, WT2);
    prep_kernel<<<dim3(128, 8, 8), dim3(32, 8), 0, stream>>>(feats, XC);

    for (int layer = 0; layer < 4; ++layer) {
        const ushort* wtqkv = WTqkv + (size_t)layer * 196608;
        const ushort* wtm = WTm + (size_t)layer * 65536;
        const ushort* wt1 = WT1 + (size_t)layer * 262144;
        const ushort* wt2 = WT2 + (size_t)layer * 131072;
        const float* lg1 = g1 + layer * DM;
        const float* lb1 = b1 + layer * DM;
        const float* lg2 = g2 + layer * DM;
        const float* lb2 = b2 + layer * DM;

        // QKV fused: [32768][768] = elu1/elu1/id( XC[:, :256] @ [Wq|Wk|Wv] )
        gemm_bf16<3><<<dim3(256, 6), 256, 0, stream>>>(XC, 512, wtqkv, QKVb, 768, 256);
        kv_kernel<<<dim3(64, 8), 256, 0, stream>>>(QKVb + 256, QKVb + 512, 768, KVp, KSp);
        kvreduce_kernel<<<64, 256, 0, stream>>>(KVp, KSp, KVT, KS);
        msg_mfma<<<dim3(64, 8), 256, 0, stream>>>(QKVb, 768, KVT, KS, msgb);
        // Wm GEMM + LN1 fused -> XC right half
        gemm_ln<0><<<512, 256, 0, stream>>>(msgb, 256, wtm, 256, lg1, lb1, nullptr, XC);
        // MLP1: relu( XC[:, :512] @ W1 ) -> HBb  (aliases QKVb, which is dead)
        gemm_bf16<2><<<dim3(256, 4), 256, 0, stream>>>(XC, 512, wt1, HBb, 512, 512);
        // MLP2 + LN2 + bf16 residual -> XC left; final layer also writes fp32 X
        gemm_ln<1><<<512, 256, 0, stream>>>(HBb, 512, wt2, 512, lg2, lb2,
                                            (layer == 3) ? X : nullptr, XC);
    }

    unprep_kernel<<<dim3(128, 8, 8), dim3(32, 8), 0, stream>>>(X, dout);
}